// Round 3
// baseline (1241.000 us; speedup 1.0000x reference)
//
#include <hip/hip_runtime.h>
#include <hip/hip_bf16.h>

#define B_ 32
#define N_ 4096
#define E_ 256
#define D_ 256
#define NS_ 8
#define LN8 2.0794415416798357f
#define OFF_ATTN 65536        // element offset of attn^T in d_out
#define OFF_S2   (65536 + 1048576)  // element offset of second slots copy
#define NSPLIT 16             // blocks per batch in mesh_kernel (256 thr each, 1 row/thr)
#define SENT 0xFFFFFFFFu      // -NaN bit pattern; clamped-finite partials never produce it

typedef unsigned short u16;
typedef __bf16 bf16x8 __attribute__((ext_vector_type(8)));
typedef float floatx4 __attribute__((ext_vector_type(4)));

__device__ __forceinline__ float bf2f(u16 h) {
  unsigned int u = ((unsigned int)h) << 16;
  return __uint_as_float(u);
}
__device__ __forceinline__ u16 f2bf(float f) {
  unsigned int u = __float_as_uint(f);
  unsigned int r = (u + 0x7FFFu + ((u >> 16) & 1u)) >> 16;
  return (u16)r;
}
__device__ __forceinline__ float ldx(const void* p, int i, int dt) {
  return dt ? ((const float*)p)[i] : bf2f(((const u16*)p)[i]);
}
__device__ __forceinline__ void stx(void* p, size_t i, int dt, float v) {
  if (dt) ((float*)p)[i] = v; else ((u16*)p)[i] = f2bf(v);
}
__device__ __forceinline__ float slog(float x) { return __logf(fmaxf(x, 1e-35f)); }
__device__ __forceinline__ float cl(float x) { return fminf(fmaxf(x, -1e30f), 1e30f); }

__device__ __forceinline__ float breduce256(float v, float* red4, int tid) {
  #pragma unroll
  for (int m = 1; m < 64; m <<= 1) v += __shfl_xor(v, m, 64);
  __syncthreads();
  if ((tid & 63) == 0) red4[tid >> 6] = v;
  __syncthreads();
  return red4[0] + red4[1] + red4[2] + red4[3];
}

// ---------------- dtype detector ----------------
__global__ void detect_dtype_kernel(const u16* __restrict__ inp, int* __restrict__ flag) {
  int lane = threadIdx.x & 63;
  int good = 0;
  for (int i = lane; i < 256; i += 64) {
    float x = bf2f(inp[i]);
    float ax = fabsf(x);
    if (x == 0.0f || (ax >= 1e-3f && ax <= 64.0f)) good++;
  }
  #pragma unroll
  for (int m = 1; m < 64; m <<= 1) good += __shfl_xor(good, m, 64);
  if (lane == 0) *flag = (good >= 208) ? 0 : 1;  // 0 = bf16, 1 = f32
}

// ---------------- prep kernels ----------------

__global__ void transpose_any_kernel(const void* __restrict__ src, u16* __restrict__ dst,
                                     int R, int C, const int* __restrict__ dtf) {
  const int dt = *dtf;
  int idx = blockIdx.x * 256 + threadIdx.x;
  if (idx >= R * C) return;
  int r = idx / C, c = idx - r * C;
  dst[c * R + r] = f2bf(ldx(src, idx, dt));
}

__global__ void cast_slots_kernel(const void* __restrict__ src, float* __restrict__ dst,
                                  const int* __restrict__ dtf) {
  const int dt = *dtf;
  int i = blockIdx.x * 256 + threadIdx.x;
  dst[i] = ldx(src, i, dt);
}

__global__ __launch_bounds__(256) void ln_stats_kernel(
    const void* __restrict__ inp, const void* __restrict__ lns, const void* __restrict__ lnb,
    const void* __restrict__ wiW, const int* __restrict__ dtf,
    float2* __restrict__ stats, float* __restrict__ logits) {
  const int dt = *dtf;
  int row = blockIdx.x * 4 + (threadIdx.x >> 6);
  int lane = threadIdx.x & 63;
  float xs[4];
  if (dt) {
    float4 h = *(const float4*)((const float*)inp + (size_t)row * E_ + lane * 4);
    xs[0] = h.x; xs[1] = h.y; xs[2] = h.z; xs[3] = h.w;
  } else {
    ushort4 h = *(const ushort4*)((const u16*)inp + (size_t)row * E_ + lane * 4);
    xs[0] = bf2f(h.x); xs[1] = bf2f(h.y); xs[2] = bf2f(h.z); xs[3] = bf2f(h.w);
  }
  float s = xs[0] + xs[1] + xs[2] + xs[3];
  float q = xs[0]*xs[0] + xs[1]*xs[1] + xs[2]*xs[2] + xs[3]*xs[3];
  #pragma unroll
  for (int m = 1; m < 64; m <<= 1) { s += __shfl_xor(s, m, 64); q += __shfl_xor(q, m, 64); }
  float mean = s * (1.0f / E_);
  float var = q * (1.0f / E_) - mean * mean;
  float rstd = rsqrtf(fmaxf(var, 0.0f) + 1e-5f);
  int e = lane * 4;
  float d = 0.0f;
  #pragma unroll
  for (int j = 0; j < 4; ++j) {
    float xn = (xs[j] - mean) * rstd * ldx(lns, e + j, dt) + ldx(lnb, e + j, dt);
    d += xn * ldx(wiW, e + j, dt);
  }
  #pragma unroll
  for (int m = 1; m < 64; m <<= 1) d += __shfl_xor(d, m, 64);
  if (lane == 0) { stats[row] = make_float2(mean, rstd); logits[row] = d; }
}

__global__ __launch_bounds__(1024) void amarg_kernel(const float* __restrict__ logits,
    float* __restrict__ log_a, float* __restrict__ inva) {
  __shared__ float red[16];
  __shared__ float bcast;
  int b = blockIdx.x, tid = threadIdx.x;
  logits += (size_t)b * N_;
  float l[4];
  #pragma unroll
  for (int i = 0; i < 4; ++i) l[i] = logits[tid + i * 1024];
  float mx = fmaxf(fmaxf(l[0], l[1]), fmaxf(l[2], l[3]));
  #pragma unroll
  for (int m = 1; m < 64; m <<= 1) mx = fmaxf(mx, __shfl_xor(mx, m, 64));
  __syncthreads();
  if ((tid & 63) == 0) red[tid >> 6] = mx;
  __syncthreads();
  if (tid == 0) { float v = red[0]; for (int i = 1; i < 16; ++i) v = fmaxf(v, red[i]); bcast = v; }
  __syncthreads();
  float M = bcast;
  float se = 0.0f;
  #pragma unroll
  for (int i = 0; i < 4; ++i) se += __expf(l[i] - M);
  #pragma unroll
  for (int m = 1; m < 64; m <<= 1) se += __shfl_xor(se, m, 64);
  __syncthreads();
  if ((tid & 63) == 0) red[tid >> 6] = se;
  __syncthreads();
  if (tid == 0) { float v = 0; for (int i = 0; i < 16; ++i) v += red[i]; bcast = v; }
  __syncthreads();
  float lgS = slog(bcast);
  #pragma unroll
  for (int i = 0; i < 4; ++i) {
    float lav = l[i] - M - lgS + LN8;
    log_a[tid + i * 1024] = lav;
    inva[tid + i * 1024] = fminf(__expf(-lav), 1e20f);
  }
}

__global__ __launch_bounds__(256, 2) void gemm_ln_kernel(
    const void* __restrict__ inp, const float2* __restrict__ stats,
    const void* __restrict__ lns, const void* __restrict__ lnb,
    const u16* __restrict__ WT, const int* __restrict__ dtf, u16* __restrict__ out) {
  __shared__ __align__(16) u16 Als[128 * 32];
  __shared__ __align__(16) u16 Bls[128 * 32];
  __shared__ float sS[256], sB[256];
  const int dt = *dtf;
  int tid = threadIdx.x;
  int m0 = blockIdx.x * 128, n0 = blockIdx.y * 128;
  sS[tid] = ldx(lns, tid, dt); sB[tid] = ldx(lnb, tid, dt);
  int w = tid >> 6, lane = tid & 63;
  int wm = (w & 1) * 64, wn = (w >> 1) * 64;
  int fr = lane & 15, kg = lane >> 4;
  floatx4 acc[4][4];
  #pragma unroll
  for (int i = 0; i < 4; ++i)
    #pragma unroll
    for (int j = 0; j < 4; ++j) acc[i][j] = (floatx4){0.f, 0.f, 0.f, 0.f};
  int sm = tid >> 1;
  int sk0 = (tid & 1) * 16;
  int grow = m0 + sm;
  float2 st = stats[grow];
  const u16* arow_h = (const u16*)inp + (size_t)grow * E_;
  const float* arow_f = (const float*)inp + (size_t)grow * E_;
  const u16* brow = WT + (size_t)(n0 + sm) * E_;
  __syncthreads();
  for (int kc = 0; kc < E_; kc += 32) {
    #pragma unroll
    for (int j = 0; j < 16; j += 4) {
      int kk = kc + sk0 + j;
      float x0, x1, x2, x3;
      if (dt) {
        float4 h = *(const float4*)(arow_f + kk);
        x0 = h.x; x1 = h.y; x2 = h.z; x3 = h.w;
      } else {
        ushort4 h = *(const ushort4*)(arow_h + kk);
        x0 = bf2f(h.x); x1 = bf2f(h.y); x2 = bf2f(h.z); x3 = bf2f(h.w);
      }
      ushort4 o;
      o.x = f2bf((x0 - st.x) * st.y * sS[kk + 0] + sB[kk + 0]);
      o.y = f2bf((x1 - st.x) * st.y * sS[kk + 1] + sB[kk + 1]);
      o.z = f2bf((x2 - st.x) * st.y * sS[kk + 2] + sB[kk + 2]);
      o.w = f2bf((x3 - st.x) * st.y * sS[kk + 3] + sB[kk + 3]);
      *(ushort4*)&Als[sm * 32 + sk0 + j] = o;
      *(ushort4*)&Bls[sm * 32 + sk0 + j] = *(const ushort4*)(brow + kk);
    }
    __syncthreads();
    bf16x8 af[4], bfv[4];
    #pragma unroll
    for (int im = 0; im < 4; ++im) af[im] = *(const bf16x8*)&Als[(wm + im * 16 + fr) * 32 + kg * 8];
    #pragma unroll
    for (int in = 0; in < 4; ++in) bfv[in] = *(const bf16x8*)&Bls[(wn + in * 16 + fr) * 32 + kg * 8];
    #pragma unroll
    for (int im = 0; im < 4; ++im)
      #pragma unroll
      for (int in = 0; in < 4; ++in)
        acc[im][in] = __builtin_amdgcn_mfma_f32_16x16x32_bf16(af[im], bfv[in], acc[im][in], 0, 0, 0);
    __syncthreads();
  }
  #pragma unroll
  for (int im = 0; im < 4; ++im)
    #pragma unroll
    for (int in = 0; in < 4; ++in)
      #pragma unroll
      for (int r = 0; r < 4; ++r) {
        int row = m0 + wm + im * 16 + kg * 4 + r;
        int col = n0 + wn + in * 16 + fr;
        out[(size_t)row * D_ + col] = f2bf(acc[im][in][r]);
      }
}

__global__ __launch_bounds__(256) void ksq_kernel(const u16* __restrict__ k, float* __restrict__ ksq) {
  int row = blockIdx.x * 4 + (threadIdx.x >> 6);
  int lane = threadIdx.x & 63;
  ushort4 h = *(const ushort4*)(k + (size_t)row * D_ + lane * 4);
  float a = bf2f(h.x), b = bf2f(h.y), c = bf2f(h.z), d = bf2f(h.w);
  float s = a * a + b * b + c * c + d * d;
  #pragma unroll
  for (int m = 1; m < 64; m <<= 1) s += __shfl_xor(s, m, 64);
  if (lane == 0) ksq[row] = s;
}

// ---------------- per-step kernels ----------------

__global__ __launch_bounds__(256) void s1_kernel(
    const float* __restrict__ slots, const void* __restrict__ lnss, const void* __restrict__ lnsb,
    const void* __restrict__ Wq, const void* __restrict__ wsW, const int* __restrict__ dtf,
    u16* __restrict__ qbfT, float* __restrict__ q_sq, float* __restrict__ logits_b) {
  __shared__ float sn_sh[256];
  __shared__ float red4[4];
  const int dt = *dtf;
  int row = blockIdx.x;
  int b = row >> 3, s = row & 7;
  int tid = threadIdx.x;
  float h = slots[(size_t)row * D_ + tid];
  float sum = breduce256(h, red4, tid);
  float sq = breduce256(h * h, red4, tid);
  float mean = sum * (1.0f / D_), var = sq * (1.0f / D_) - mean * mean;
  float rstd = rsqrtf(fmaxf(var, 0.0f) + 1e-5f);
  float sn = (h - mean) * rstd * ldx(lnss, tid, dt) + ldx(lnsb, tid, dt);
  sn_sh[tid] = sn;
  __syncthreads();
  float acc = 0.0f;
  if (dt) {
    const float* W = (const float*)Wq;
    for (int d = 0; d < 256; ++d) acc += sn_sh[d] * W[d * 256 + tid];
  } else {
    const u16* W = (const u16*)Wq;
    for (int d = 0; d < 256; ++d) acc += sn_sh[d] * bf2f(W[d * 256 + tid]);
  }
  qbfT[(size_t)(b * 16 + s) * 256 + tid] = f2bf(acc);
  float qs = breduce256(acc * acc, red4, tid);
  float lbp = breduce256(sn * ldx(wsW, tid, dt), red4, tid);
  if (tid == 0) { q_sq[row] = qs; logits_b[row] = lbp; }
}

__global__ void bmarg_kernel(const float* __restrict__ logits_b, const void* __restrict__ wsb,
                             const int* __restrict__ dtf, float* __restrict__ log_b) {
  int b = threadIdx.x;
  if (b >= 32) return;
  float off = ldx(wsb, 0, *dtf);
  float l[8], M = -1e30f;
  #pragma unroll
  for (int s = 0; s < 8; ++s) { l[s] = logits_b[b * 8 + s] + off; M = fmaxf(M, l[s]); }
  float S = 0.0f;
  #pragma unroll
  for (int s = 0; s < 8; ++s) S += __expf(l[s] - M);
  float lgS = slog(S);
  #pragma unroll
  for (int s = 0; s < 8; ++s) log_b[b * 8 + s] = l[s] - M - lgS + LN8;
}

__global__ __launch_bounds__(256) void d2c_kernel(
    const u16* __restrict__ kbf, const u16* __restrict__ qbfT,
    const float* __restrict__ ksq, const float* __restrict__ qsq, float* __restrict__ C) {
  int b = blockIdx.y;
  int tid = threadIdx.x;
  int w = tid >> 6, lane = tid & 63;
  int m0 = blockIdx.x * 64 + w * 16;
  int fr = lane & 15, kg = lane >> 4;
  const u16* kp = kbf + ((size_t)(b * N_ + m0 + fr)) * D_;
  const u16* qp = qbfT + (size_t)(b * 16 + fr) * D_;
  floatx4 acc = (floatx4){0.f, 0.f, 0.f, 0.f};
  #pragma unroll
  for (int kc = 0; kc < D_; kc += 32) {
    bf16x8 a = *(const bf16x8*)(kp + kc + kg * 8);
    bf16x8 bb = *(const bf16x8*)(qp + kc + kg * 8);
    acc = __builtin_amdgcn_mfma_f32_16x16x32_bf16(a, bb, acc, 0, 0, 0);
  }
  if (fr < 8) {
    #pragma unroll
    for (int r = 0; r < 4; ++r) {
      int n = m0 + kg * 4 + r;
      float d2 = ksq[b * N_ + n] + qsq[b * 8 + fr] - 2.0f * acc[r];
      C[((size_t)(b * N_ + n)) * 8 + fr] = sqrtf(fmaxf(d2, 1e-12f));
    }
  }
}

// ---- cross-block group reduction, sentinel-flag protocol (16 blocks/batch) ----
// Slots pre-armed to SENT by hipMemsetAsync.  Partials are clamped-finite
// (|elem| <= 1e30, 256-elem block sums <= 2.6e32, 16-block sums <= 4.2e33 --
// never inf/NaN), so the value itself is the arrival flag.  Every block reads
// the same 128 finalized slots and applies the identical pair+butterfly tree,
// so evP/dv are bit-identical across blocks.  rp < 64 fresh slots: no ABA.
// Blocks of one batch are XCD-co-located via grid(b fastest): flattened id =
// b + 32*s -> id%8 = b%8 under the observed round-robin XCD mapping (perf
// heuristic only; correctness does not depend on placement).
__device__ __forceinline__ float grp_sync_reduce(
    float acc8[8], float (*red)[8],
    unsigned int* gp, int rp, int blkn, int wv, int lane, int tid) {
  #pragma unroll
  for (int m = 1; m < 64; m <<= 1)
    #pragma unroll
    for (int s = 0; s < 8; ++s) acc8[s] += __shfl_xor(acc8[s], m, 64);
  if (lane == 0)
    #pragma unroll
    for (int s = 0; s < 8; ++s) red[wv][s] = acc8[s];
  __syncthreads();
  float x = 0.0f;
  if (tid < 64) {  // wave 0 only; waves 1-3 park at the caller's __syncthreads
    // block partial for col (tid&7): sum red[w][c] over the 4 waves
    float v = (tid < 32) ? red[tid >> 3][tid & 7] : 0.0f;
    v += __shfl_xor(v, 8, 64);
    v += __shfl_xor(v, 16, 64);
    if (tid < 8)
      __hip_atomic_store(gp + rp * 128 + blkn * 8 + tid, __float_as_uint(v),
                         __ATOMIC_RELAXED, __HIP_MEMORY_SCOPE_AGENT);
    // poll all 128 slots (16 blocks x 8 cols), 2 coalesced loads per iteration
    unsigned int u0, u1;
    for (;;) {
      u0 = __hip_atomic_load(gp + rp * 128 + tid, __ATOMIC_RELAXED, __HIP_MEMORY_SCOPE_AGENT);
      u1 = __hip_atomic_load(gp + rp * 128 + 64 + tid, __ATOMIC_RELAXED, __HIP_MEMORY_SCOPE_AGENT);
      if (__all((u0 != SENT) && (u1 != SENT))) break;
      __builtin_amdgcn_s_sleep(1);
    }
    x = __uint_as_float(u0) + __uint_as_float(u1);  // blocks i and i+8, same col
    x += __shfl_xor(x, 8, 64);   // sum across the 8 lane-groups (block pairs)
    x += __shfl_xor(x, 16, 64);
    x += __shfl_xor(x, 32, 64);
    // lanes 0..7 now hold the full column sums for cols 0..7
  }
  return x;
}

__global__ __launch_bounds__(256, 2) void mesh_kernel(
    const float* __restrict__ Cg, const float* __restrict__ log_a_g,
    const float* __restrict__ inva_g, const float* __restrict__ log_b_g,
    const int* __restrict__ dtf,
    unsigned int* __restrict__ gpart,
    float* __restrict__ attn, void* __restrict__ dout_or_null) {
  const int b = blockIdx.x;               // batch (fast dim -> XCD co-location)
  const int blkn = blockIdx.y;            // 0..NSPLIT-1: which 256-row slice
  const int tid = threadIdx.x;
  const int dt = *dtf;
  const int n = blkn * 256 + tid;         // this thread's single row

  Cg += ((size_t)b * N_ + n) * 8;
  const float la = log_a_g[(size_t)b * N_ + n];
  const float ia = inva_g[(size_t)b * N_ + n];
  log_b_g += b * 8;
  attn += (size_t)b * N_ * 8;
  unsigned int* gp = gpart + (size_t)b * 64 * 128;

  __shared__ float evP[6][8];
  __shared__ float lb[8], invb[8];
  __shared__ float dv[8];
  __shared__ float red[4][8];

  if (tid < 8) { float x = log_b_g[tid]; lb[tid] = x; invb[tid] = fminf(__expf(-x), 1e20f); }

  float E[8], dK[8], eus[5];
  float eu = 0.0f, dup = 0.0f;
  {
    float4 c0 = *(const float4*)(Cg);
    float4 c1 = *(const float4*)(Cg + 4);
    E[0] = __expf(-c0.x); E[1] = __expf(-c0.y); E[2] = __expf(-c0.z); E[3] = __expf(-c0.w);
    E[4] = __expf(-c1.x); E[5] = __expf(-c1.y); E[6] = __expf(-c1.z); E[7] = __expf(-c1.w);
  }
  __syncthreads();

  const int wv = tid >> 6, lane = tid & 63;
  int rp = 0;

  for (int mesh = 0; mesh < 4; ++mesh) {
    if (tid < 8) evP[0][tid] = 1.0f;
    __syncthreads();
    // ---- forward sinkhorn (5 iters) ----
    for (int t = 1; t <= 5; ++t) {
      float evp[8];
      #pragma unroll
      for (int s = 0; s < 8; ++s) evp[s] = evP[t - 1][s];
      float su = 0.0f;
      #pragma unroll
      for (int s = 0; s < 8; ++s) su += fminf(E[s] * evp[s], 1e30f);
      float u = la - slog(su);
      eu = fminf(__expf(u), 1e20f);
      eus[t - 1] = eu;                    // eu history in registers
      float acc8[8];
      #pragma unroll
      for (int s = 0; s < 8; ++s) acc8[s] = fminf(E[s] * eu, 1e30f);
      float S = grp_sync_reduce(acc8, red, gp, rp, blkn, wv, lane, tid);
      if (tid < 8) {
        float v = lb[tid] - slog(S);
        evP[t][tid] = fminf(__expf(v), 1e20f);
      }
      ++rp;
      __syncthreads();
    }
    // ---- entropy gradient ----
    {
      float ev5[8];
      #pragma unroll
      for (int s = 0; s < 8; ++s) ev5[s] = evP[5][s];
      float acc8[8];
      dup = 0.0f;
      #pragma unroll
      for (int s = 0; s < 8; ++s) {
        float t1 = fminf(E[s] * eu, 1e30f);
        float P = fminf(t1 * ev5[s], 1e30f);
        float Pe = P + 1e-8f;
        float g = -(__logf(Pe) + P / Pe) * P;
        dK[s] = g; dup += g; acc8[s] = g;
      }
      float S = grp_sync_reduce(acc8, red, gp, rp, blkn, wv, lane, tid);
      if (tid < 8) dv[tid] = cl(S);
      ++rp;
      __syncthreads();
    }
    // ---- backward (t = 5..1; cross-block reduce only needed for t > 1) ----
    for (int t = 5; t >= 1; --t) {
      float evt[8], evtm[8], dvl[8], ibl[8];
      #pragma unroll
      for (int s = 0; s < 8; ++s) { evt[s] = evP[t][s]; evtm[s] = evP[t - 1][s]; dvl[s] = dv[s]; ibl[s] = invb[s]; }
      float eut = eus[t - 1];
      float duv = 0.0f;
      float w8[8];
      #pragma unroll
      for (int s = 0; s < 8; ++s) {
        float a1 = fminf(E[s] * eut, 1e30f);
        float b1 = fminf(a1 * evt[s], 1e30f);
        w8[s] = fminf(b1 * ibl[s], 1e30f);
        duv += cl(dvl[s] * w8[s]);
      }
      float du = ((t == 5) ? dup : 0.0f) - duv;
      float duf = cl(cl(du * ia) * eut);
      float acc8[8];
      #pragma unroll
      for (int s = 0; s < 8; ++s) {
        float ee = fminf(E[s] * evtm[s], 1e30f);
        float zc = cl(ee * duf);
        dK[s] -= cl(dvl[s] * w8[s]) + zc;
        acc8[s] = -zc;
      }
      if (t > 1) {
        float S = grp_sync_reduce(acc8, red, gp, rp, blkn, wv, lane, tid);
        if (tid < 8) dv[tid] = cl(S);
        ++rp;
      }
      __syncthreads();  // also protects evP[0] rewrite at next mesh iter
    }
    // ---- cost update ----
    #pragma unroll
    for (int s = 0; s < 8; ++s) {
      float dkc = fminf(fmaxf(dK[s], -4.0f), 4.0f);
      float Enew = E[s] * __expf(-5.0f * dkc);
      E[s] = fminf(fmaxf(Enew, 1e-35f), 1e30f);
    }
  }

  // ---- final sinkhorn (10 iters) ----
  if (tid < 8) evP[0][tid] = 1.0f;
  __syncthreads();
  for (int t = 1; t <= 10; ++t) {
    int pc = (t - 1) & 1, cc = t & 1;
    float evp[8];
    #pragma unroll
    for (int s = 0; s < 8; ++s) evp[s] = evP[pc][s];
    float su = 0.0f;
    #pragma unroll
    for (int s = 0; s < 8; ++s) su += fminf(E[s] * evp[s], 1e30f);
    eu = fminf(__expf(la - slog(su)), 1e20f);
    float acc8[8];
    #pragma unroll
    for (int s = 0; s < 8; ++s) acc8[s] = fminf(E[s] * eu, 1e30f);
    float S = grp_sync_reduce(acc8, red, gp, rp, blkn, wv, lane, tid);
    if (tid < 8) {
      float v = lb[tid] - slog(S);
      evP[cc][tid] = fminf(__expf(v), 1e20f);
    }
    ++rp;
    __syncthreads();
  }
  float evf[8];
  #pragma unroll
  for (int s = 0; s < 8; ++s) evf[s] = evP[0][s];
  float pv[8];
  #pragma unroll
  for (int s = 0; s < 8; ++s) {
    float t1 = fminf(E[s] * eu, 1e30f);
    pv[s] = fminf(t1 * evf[s], 1e30f);
  }
  *(float4*)(attn + (size_t)n * 8) = make_float4(pv[0], pv[1], pv[2], pv[3]);
  *(float4*)(attn + (size_t)n * 8 + 4) = make_float4(pv[4], pv[5], pv[6], pv[7]);
  if (dout_or_null) {
    #pragma unroll
    for (int s = 0; s < 8; ++s)
      stx(dout_or_null, (size_t)OFF_ATTN + ((size_t)b * 8 + s) * N_ + n, dt, pv[s]);
  }
}

__global__ __launch_bounds__(256) void upd_kernel(
    const float* __restrict__ attn, const u16* __restrict__ vbf, float* __restrict__ updp) {
  int chunk = blockIdx.x, b = blockIdx.y, d = threadIdx.x;
  const float* ap = attn + ((size_t)b * N_ + chunk * 512) * 8;
  const u16* vp = vbf + ((size_t)b * N_ + chunk * 512) * D_ + d;
  float acc[8] = {0, 0, 0, 0, 0, 0, 0, 0};
  for (int i = 0; i < 512; ++i) {
    float4 a0 = *(const float4*)(ap + (size_t)i * 8);
    float4 a1 = *(const float4*)(ap + (size_t)i * 8 + 4);
    float vv = bf2f(vp[(size_t)i * D_]);
    acc[0] += a0.x * vv; acc[1] += a0.y * vv; acc[2] += a0.z * vv; acc[3] += a0.w * vv;
    acc[4] += a1.x * vv; acc[5] += a1.y * vv; acc[6] += a1.z * vv; acc[7] += a1.w * vv;
  }
  #pragma unroll
  for (int s = 0; s < 8; ++s)
    updp[(((size_t)b * 8 + chunk) * 8 + s) * D_ + d] = acc[s];
}

__global__ __launch_bounds__(256) void gru_mlp_kernel(
    const float* __restrict__ updp, const float* __restrict__ slots_cur,
    const u16* __restrict__ WihT, const u16* __restrict__ WhhT,
    const void* __restrict__ bih, const void* __restrict__ bhh,
    const void* __restrict__ lnms, const void* __restrict__ lnmb,
    const void* __restrict__ W1, const void* __restrict__ b1,
    const void* __restrict__ W2, const void* __restrict__ b2,
    const int* __restrict__ dtf,
    float* __restrict__ slots_next, void* __restrict__ dout_or_null) {
  __shared__ float xs[256], hs[256], hns[256], as_[256];
  __shared__ float red4[4];
  const int dt = *dtf;
  int row = blockIdx.x;
  int b = row >> 3, s = row & 7;
  int tid = threadIdx.x;
  float x = 0.0f;
  #pragma unroll
  for (int c = 0; c < 8; ++c) x += updp[(((size_t)b * 8 + c) * 8 + s) * D_ + tid];
  float h = slots_cur[(size_t)row * D_ + tid];
  xs[tid] = x; hs[tid] = h;
  __syncthreads();
  float gr = ldx(bih, tid, dt), gz = ldx(bih, 256 + tid, dt), gn = ldx(bih, 512 + tid, dt);
  float hr = ldx(bhh, tid, dt), hz = ldx(bhh, 256 + tid, dt), hn_ = ldx(bhh, 512 + tid, dt);
  for (int e = 0; e < 256; ++e) {
    float xe = xs[e], he = hs[e];
    const u16* wi = WihT + e * 768;
    const u16* wh = WhhT + e * 768;
    gr += xe * bf2f(wi[tid]); gz += xe * bf2f(wi[256 + tid]); gn += xe * bf2f(wi[512 + tid]);
    hr += he * bf2f(wh[tid]); hz += he * bf2f(wh[256 + tid]); hn_ += he * bf2f(wh[512 + tid]);
  }
  float r = 1.0f / (1.0f + __expf(-(gr + hr)));
  float z = 1.0f / (1.0f + __expf(-(gz + hz)));
  float nn = tanhf(gn + r * hn_);
  float h2 = (1.0f - z) * nn + z * h;
  float sum = breduce256(h2, red4, tid);
  float sq = breduce256(h2 * h2, red4, tid);
  float mean = sum * (1.0f / D_), var = sq * (1.0f / D_) - mean * mean;
  float rstd = rsqrtf(fmaxf(var, 0.0f) + 1e-5f);
  float hn2 = (h2 - mean) * rstd * ldx(lnms, tid, dt) + ldx(lnmb, tid, dt);
  hns[tid] = hn2;
  __syncthreads();
  float a1 = ldx(b1, tid, dt);
  if (dt) {
    const float* W = (const float*)W1;
    for (int e = 0; e < 256; ++e) a1 += hns[e] * W[e * 256 + tid];
  } else {
    const u16* W = (const u16*)W1;
    for (int e = 0; e < 256; ++e) a1 += hns[e] * bf2f(W[e * 256 + tid]);
  }
  a1 = fmaxf(a1, 0.0f);
  as_[tid] = a1;
  __syncthreads();
  float o = h2 + ldx(b2, tid, dt);
  if (dt) {
    const float* W = (const float*)W2;
    for (int e = 0; e < 256; ++e) o += as_[e] * W[e * 256 + tid];
  } else {
    const u16* W = (const u16*)W2;
    for (int e = 0; e < 256; ++e) o += as_[e] * bf2f(W[e * 256 + tid]);
  }
  slots_next[(size_t)row * D_ + tid] = o;
  if (dout_or_null) {
    stx(dout_or_null, (size_t)row * D_ + tid, dt, o);
    stx(dout_or_null, (size_t)OFF_S2 + (size_t)row * D_ + tid, dt, o);
  }
}

// ---------------- host ----------------

extern "C" void kernel_launch(void* const* d_in, const int* in_sizes, int n_in,
                              void* d_out, int out_size, void* d_ws, size_t ws_size,
                              hipStream_t stream) {
  (void)in_sizes; (void)n_in; (void)out_size;
  const void* inp      = d_in[0];
  const void* slots0   = d_in[1];
  const void* ln_in_s  = d_in[2];
  const void* ln_in_b  = d_in[3];
  const void* ln_sl_s  = d_in[4];
  const void* ln_sl_b  = d_in[5];
  const void* ln_mlp_s = d_in[6];
  const void* ln_mlp_b = d_in[7];
  const void* Wq  = d_in[8];
  const void* Wk  = d_in[9];
  const void* Wv  = d_in[10];
  const void* wiW = d_in[11];
  const void* wsW = d_in[13];
  const void* wsb = d_in[14];
  const void* Wih = d_in[15];
  const void* Whh = d_in[16];
  const void* bih = d_in[17];
  const void* bhh = d_in[18];
  const void* W1  = d_in[19];
  const void* b1  = d_in[20];
  const void* W2  = d_in[21];
  const void* b2  = d_in[22];

  char* ws = (char*)d_ws;
  size_t off = 0;
  auto alloc = [&](size_t bytes) -> void* {
    void* p = ws + off;
    off += (bytes + 255) & ~(size_t)255;
    return p;
  };
  const size_t NR = (size_t)B_ * N_;
  int* dtflag     = (int*)alloc(256);
  float2* stats   = (float2*)alloc(NR * sizeof(float2));
  float* logits_a = (float*)alloc(NR * 4);
  float* log_a    = (float*)alloc(NR * 4);
  float* inva     = (float*)alloc(NR * 4);
  u16* kbf        = (u16*)alloc(NR * D_ * 2);
  u16* vbf        = (u16*)alloc(NR * D_ * 2);
  float* ksq      = (float*)alloc(NR * 4);
  u16* WkT        = (u16*)alloc(E_ * D_ * 2);
  u16* WvT        = (u16*)alloc(E_ * D_ * 2);
  u16* WihT       = (u16*)alloc(768 * 256 * 2);
  u16* WhhT       = (u16*)alloc(768 * 256 * 2);
  u16* qbfT       = (u16*)alloc((size_t)B_ * 16 * 256 * 2);
  float* q_sq     = (float*)alloc(B_ * 8 * 4);
  float* logits_b = (float*)alloc(B_ * 8 * 4);
  float* log_b    = (float*)alloc(B_ * 8 * 4);
  float* Cbuf     = (float*)alloc(NR * 8 * 4);
  float* attnb    = (float*)alloc(NR * 8 * 4);
  float* updp     = (float*)alloc((size_t)B_ * 8 * 8 * D_ * 4);
  float* slots_a  = (float*)alloc((size_t)B_ * 8 * D_ * 4);
  float* slots_b  = (float*)alloc((size_t)B_ * 8 * D_ * 4);
  // sentinel-armed reduction slots: per step, per batch, 64 points x 128 dwords
  unsigned int* gpart = (unsigned int*)alloc((size_t)3 * B_ * 64 * 128 * 4);
  if (ws_size < off) return;  // sentinel: absmax==0.934 next round => ws shortage

  hipMemsetAsync(gpart, 0xFF, (size_t)3 * B_ * 64 * 128 * 4, stream);  // arm all slots
  detect_dtype_kernel<<<1, 64, 0, stream>>>((const u16*)inp, dtflag);

  transpose_any_kernel<<<(E_ * D_ + 255) / 256, 256, 0, stream>>>(Wk, WkT, E_, D_, dtflag);
  transpose_any_kernel<<<(E_ * D_ + 255) / 256, 256, 0, stream>>>(Wv, WvT, E_, D_, dtflag);
  transpose_any_kernel<<<(768 * 256 + 255) / 256, 256, 0, stream>>>(Wih, WihT, 768, 256, dtflag);
  transpose_any_kernel<<<(768 * 256 + 255) / 256, 256, 0, stream>>>(Whh, WhhT, 768, 256, dtflag);
  cast_slots_kernel<<<(B_ * 8 * D_) / 256, 256, 0, stream>>>(slots0, slots_a, dtflag);
  hipMemsetAsync(qbfT, 0, (size_t)B_ * 16 * 256 * 2, stream);
  ln_stats_kernel<<<NR / 4, 256, 0, stream>>>(inp, ln_in_s, ln_in_b, wiW, dtflag, stats, logits_a);
  amarg_kernel<<<B_, 1024, 0, stream>>>(logits_a, log_a, inva);
  gemm_ln_kernel<<<dim3(NR / 128, 2), 256, 0, stream>>>(inp, stats, ln_in_s, ln_in_b, WkT, dtflag, kbf);
  gemm_ln_kernel<<<dim3(NR / 128, 2), 256, 0, stream>>>(inp, stats, ln_in_s, ln_in_b, WvT, dtflag, vbf);
  ksq_kernel<<<NR / 4, 256, 0, stream>>>(kbf, ksq);

  float* scur = slots_a;
  float* snext = slots_b;
  for (int step = 0; step < 3; ++step) {
    bool last = (step == 2);
    s1_kernel<<<B_ * 8, 256, 0, stream>>>(scur, ln_sl_s, ln_sl_b, Wq, wsW, dtflag, qbfT, q_sq, logits_b);
    bmarg_kernel<<<1, 32, 0, stream>>>(logits_b, wsb, dtflag, log_b);
    d2c_kernel<<<dim3(N_ / 64, B_), 256, 0, stream>>>(kbf, qbfT, ksq, q_sq, Cbuf);
    mesh_kernel<<<dim3(B_, NSPLIT), 256, 0, stream>>>(Cbuf, log_a, inva, log_b, dtflag,
                                                      gpart + (size_t)step * B_ * 64 * 128,
                                                      attnb, last ? d_out : (void*)nullptr);
    upd_kernel<<<dim3(8, B_), 256, 0, stream>>>(attnb, vbf, updp);
    gru_mlp_kernel<<<B_ * 8, 256, 0, stream>>>(updp, scur, WihT, WhhT, bih, bhh,
                                               ln_mlp_s, ln_mlp_b, W1, b1, W2, b2, dtflag, snext,
                                               last ? d_out : (void*)nullptr);
    float* t = scur; scur = snext; snext = t;
  }
}

// Round 4
// 1107.719 us; speedup vs baseline: 1.1203x; 1.1203x over previous
//
#include <hip/hip_runtime.h>
#include <hip/hip_bf16.h>

#define B_ 32
#define N_ 4096
#define E_ 256
#define D_ 256
#define NS_ 8
#define LN8 2.0794415416798357f
#define OFF_ATTN 65536        // element offset of attn^T in d_out
#define OFF_S2   (65536 + 1048576)  // element offset of second slots copy
#define NSPLIT 8              // blocks per batch in mesh_kernel (512 thr, 1 row/thr)
#define SENT 0xFFFFFFFFu      // -NaN bit pattern; clamped-finite partials never produce it

typedef unsigned short u16;
typedef unsigned short u16x8 __attribute__((ext_vector_type(8)));
typedef __bf16 bf16x8 __attribute__((ext_vector_type(8)));
typedef float floatx4 __attribute__((ext_vector_type(4)));

__device__ __forceinline__ float bf2f(u16 h) {
  unsigned int u = ((unsigned int)h) << 16;
  return __uint_as_float(u);
}
__device__ __forceinline__ u16 f2bf(float f) {
  unsigned int u = __float_as_uint(f);
  unsigned int r = (u + 0x7FFFu + ((u >> 16) & 1u)) >> 16;
  return (u16)r;
}
__device__ __forceinline__ float ldx(const void* p, int i, int dt) {
  return dt ? ((const float*)p)[i] : bf2f(((const u16*)p)[i]);
}
__device__ __forceinline__ void stx(void* p, size_t i, int dt, float v) {
  if (dt) ((float*)p)[i] = v; else ((u16*)p)[i] = f2bf(v);
}
__device__ __forceinline__ float slog(float x) { return __logf(fmaxf(x, 1e-35f)); }
__device__ __forceinline__ float cl(float x) { return fminf(fmaxf(x, -1e30f), 1e30f); }

__device__ __forceinline__ float breduce256(float v, float* red4, int tid) {
  #pragma unroll
  for (int m = 1; m < 64; m <<= 1) v += __shfl_xor(v, m, 64);
  __syncthreads();
  if ((tid & 63) == 0) red4[tid >> 6] = v;
  __syncthreads();
  return red4[0] + red4[1] + red4[2] + red4[3];
}

// ---------------- dtype detector ----------------
__global__ void detect_dtype_kernel(const u16* __restrict__ inp, int* __restrict__ flag) {
  int lane = threadIdx.x & 63;
  int good = 0;
  for (int i = lane; i < 256; i += 64) {
    float x = bf2f(inp[i]);
    float ax = fabsf(x);
    if (x == 0.0f || (ax >= 1e-3f && ax <= 64.0f)) good++;
  }
  #pragma unroll
  for (int m = 1; m < 64; m <<= 1) good += __shfl_xor(good, m, 64);
  if (lane == 0) *flag = (good >= 208) ? 0 : 1;  // 0 = bf16, 1 = f32
}

// ---------------- prep kernels ----------------

__global__ void transpose_any_kernel(const void* __restrict__ src, u16* __restrict__ dst,
                                     int R, int C, const int* __restrict__ dtf) {
  const int dt = *dtf;
  int idx = blockIdx.x * 256 + threadIdx.x;
  if (idx >= R * C) return;
  int r = idx / C, c = idx - r * C;
  dst[c * R + r] = f2bf(ldx(src, idx, dt));
}

__global__ void cast_slots_kernel(const void* __restrict__ src, float* __restrict__ dst,
                                  const int* __restrict__ dtf) {
  const int dt = *dtf;
  int i = blockIdx.x * 256 + threadIdx.x;
  dst[i] = ldx(src, i, dt);
}

__global__ __launch_bounds__(256) void ln_stats_kernel(
    const void* __restrict__ inp, const void* __restrict__ lns, const void* __restrict__ lnb,
    const void* __restrict__ wiW, const int* __restrict__ dtf,
    float2* __restrict__ stats, float* __restrict__ logits) {
  const int dt = *dtf;
  int row = blockIdx.x * 4 + (threadIdx.x >> 6);
  int lane = threadIdx.x & 63;
  float xs[4];
  if (dt) {
    float4 h = *(const float4*)((const float*)inp + (size_t)row * E_ + lane * 4);
    xs[0] = h.x; xs[1] = h.y; xs[2] = h.z; xs[3] = h.w;
  } else {
    ushort4 h = *(const ushort4*)((const u16*)inp + (size_t)row * E_ + lane * 4);
    xs[0] = bf2f(h.x); xs[1] = bf2f(h.y); xs[2] = bf2f(h.z); xs[3] = bf2f(h.w);
  }
  float s = xs[0] + xs[1] + xs[2] + xs[3];
  float q = xs[0]*xs[0] + xs[1]*xs[1] + xs[2]*xs[2] + xs[3]*xs[3];
  #pragma unroll
  for (int m = 1; m < 64; m <<= 1) { s += __shfl_xor(s, m, 64); q += __shfl_xor(q, m, 64); }
  float mean = s * (1.0f / E_);
  float var = q * (1.0f / E_) - mean * mean;
  float rstd = rsqrtf(fmaxf(var, 0.0f) + 1e-5f);
  int e = lane * 4;
  float d = 0.0f;
  #pragma unroll
  for (int j = 0; j < 4; ++j) {
    float xn = (xs[j] - mean) * rstd * ldx(lns, e + j, dt) + ldx(lnb, e + j, dt);
    d += xn * ldx(wiW, e + j, dt);
  }
  #pragma unroll
  for (int m = 1; m < 64; m <<= 1) d += __shfl_xor(d, m, 64);
  if (lane == 0) { stats[row] = make_float2(mean, rstd); logits[row] = d; }
}

__global__ __launch_bounds__(1024) void amarg_kernel(const float* __restrict__ logits,
    float* __restrict__ log_a, float* __restrict__ inva) {
  __shared__ float red[16];
  __shared__ float bcast;
  int b = blockIdx.x, tid = threadIdx.x;
  logits += (size_t)b * N_;
  float l[4];
  #pragma unroll
  for (int i = 0; i < 4; ++i) l[i] = logits[tid + i * 1024];
  float mx = fmaxf(fmaxf(l[0], l[1]), fmaxf(l[2], l[3]));
  #pragma unroll
  for (int m = 1; m < 64; m <<= 1) mx = fmaxf(mx, __shfl_xor(mx, m, 64));
  __syncthreads();
  if ((tid & 63) == 0) red[tid >> 6] = mx;
  __syncthreads();
  if (tid == 0) { float v = red[0]; for (int i = 1; i < 16; ++i) v = fmaxf(v, red[i]); bcast = v; }
  __syncthreads();
  float M = bcast;
  float se = 0.0f;
  #pragma unroll
  for (int i = 0; i < 4; ++i) se += __expf(l[i] - M);
  #pragma unroll
  for (int m = 1; m < 64; m <<= 1) se += __shfl_xor(se, m, 64);
  __syncthreads();
  if ((tid & 63) == 0) red[tid >> 6] = se;
  __syncthreads();
  if (tid == 0) { float v = 0; for (int i = 0; i < 16; ++i) v += red[i]; bcast = v; }
  __syncthreads();
  float lgS = slog(bcast);
  #pragma unroll
  for (int i = 0; i < 4; ++i) {
    float lav = l[i] - M - lgS + LN8;
    log_a[tid + i * 1024] = lav;
    inva[tid + i * 1024] = fminf(__expf(-lav), 1e20f);
  }
}

__global__ __launch_bounds__(256, 2) void gemm_ln_kernel(
    const void* __restrict__ inp, const float2* __restrict__ stats,
    const void* __restrict__ lns, const void* __restrict__ lnb,
    const u16* __restrict__ WT, const int* __restrict__ dtf, u16* __restrict__ out) {
  __shared__ __align__(16) u16 Als[128 * 32];
  __shared__ __align__(16) u16 Bls[128 * 32];
  __shared__ float sS[256], sB[256];
  const int dt = *dtf;
  int tid = threadIdx.x;
  int m0 = blockIdx.x * 128, n0 = blockIdx.y * 128;
  sS[tid] = ldx(lns, tid, dt); sB[tid] = ldx(lnb, tid, dt);
  int w = tid >> 6, lane = tid & 63;
  int wm = (w & 1) * 64, wn = (w >> 1) * 64;
  int fr = lane & 15, kg = lane >> 4;
  floatx4 acc[4][4];
  #pragma unroll
  for (int i = 0; i < 4; ++i)
    #pragma unroll
    for (int j = 0; j < 4; ++j) acc[i][j] = (floatx4){0.f, 0.f, 0.f, 0.f};
  int sm = tid >> 1;
  int sk0 = (tid & 1) * 16;
  int grow = m0 + sm;
  float2 st = stats[grow];
  const u16* arow_h = (const u16*)inp + (size_t)grow * E_;
  const float* arow_f = (const float*)inp + (size_t)grow * E_;
  const u16* brow = WT + (size_t)(n0 + sm) * E_;
  __syncthreads();
  for (int kc = 0; kc < E_; kc += 32) {
    #pragma unroll
    for (int j = 0; j < 16; j += 4) {
      int kk = kc + sk0 + j;
      float x0, x1, x2, x3;
      if (dt) {
        float4 h = *(const float4*)(arow_f + kk);
        x0 = h.x; x1 = h.y; x2 = h.z; x3 = h.w;
      } else {
        ushort4 h = *(const ushort4*)(arow_h + kk);
        x0 = bf2f(h.x); x1 = bf2f(h.y); x2 = bf2f(h.z); x3 = bf2f(h.w);
      }
      ushort4 o;
      o.x = f2bf((x0 - st.x) * st.y * sS[kk + 0] + sB[kk + 0]);
      o.y = f2bf((x1 - st.x) * st.y * sS[kk + 1] + sB[kk + 1]);
      o.z = f2bf((x2 - st.x) * st.y * sS[kk + 2] + sB[kk + 2]);
      o.w = f2bf((x3 - st.x) * st.y * sS[kk + 3] + sB[kk + 3]);
      *(ushort4*)&Als[sm * 32 + sk0 + j] = o;
      *(ushort4*)&Bls[sm * 32 + sk0 + j] = *(const ushort4*)(brow + kk);
    }
    __syncthreads();
    bf16x8 af[4], bfv[4];
    #pragma unroll
    for (int im = 0; im < 4; ++im) af[im] = *(const bf16x8*)&Als[(wm + im * 16 + fr) * 32 + kg * 8];
    #pragma unroll
    for (int in = 0; in < 4; ++in) bfv[in] = *(const bf16x8*)&Bls[(wn + in * 16 + fr) * 32 + kg * 8];
    #pragma unroll
    for (int im = 0; im < 4; ++im)
      #pragma unroll
      for (int in = 0; in < 4; ++in)
        acc[im][in] = __builtin_amdgcn_mfma_f32_16x16x32_bf16(af[im], bfv[in], acc[im][in], 0, 0, 0);
    __syncthreads();
  }
  #pragma unroll
  for (int im = 0; im < 4; ++im)
    #pragma unroll
    for (int in = 0; in < 4; ++in)
      #pragma unroll
      for (int r = 0; r < 4; ++r) {
        int row = m0 + wm + im * 16 + kg * 4 + r;
        int col = n0 + wn + in * 16 + fr;
        out[(size_t)row * D_ + col] = f2bf(acc[im][in][r]);
      }
}

// ---------------- per-step kernels ----------------

__global__ __launch_bounds__(256) void s1_kernel(
    const float* __restrict__ slots, const void* __restrict__ lnss, const void* __restrict__ lnsb,
    const void* __restrict__ Wq, const void* __restrict__ wsW, const int* __restrict__ dtf,
    float* __restrict__ qf, float* __restrict__ q_sq, float* __restrict__ logits_b) {
  __shared__ float sn_sh[256];
  __shared__ float red4[4];
  const int dt = *dtf;
  int row = blockIdx.x;
  int tid = threadIdx.x;
  float h = slots[(size_t)row * D_ + tid];
  float sum = breduce256(h, red4, tid);
  float sq = breduce256(h * h, red4, tid);
  float mean = sum * (1.0f / D_), var = sq * (1.0f / D_) - mean * mean;
  float rstd = rsqrtf(fmaxf(var, 0.0f) + 1e-5f);
  float sn = (h - mean) * rstd * ldx(lnss, tid, dt) + ldx(lnsb, tid, dt);
  sn_sh[tid] = sn;
  __syncthreads();
  float acc = 0.0f;
  if (dt) {
    const float* W = (const float*)Wq;
    for (int d = 0; d < 256; ++d) acc += sn_sh[d] * W[d * 256 + tid];
  } else {
    const u16* W = (const u16*)Wq;
    for (int d = 0; d < 256; ++d) acc += sn_sh[d] * bf2f(W[d * 256 + tid]);
  }
  qf[(size_t)row * 256 + tid] = acc;   // f32 q, row = b*8 + s
  float qs = breduce256(acc * acc, red4, tid);
  float lbp = breduce256(sn * ldx(wsW, tid, dt), red4, tid);
  if (tid == 0) { q_sq[row] = qs; logits_b[row] = lbp; }
}

__global__ void bmarg_kernel(const float* __restrict__ logits_b, const void* __restrict__ wsb,
                             const int* __restrict__ dtf, float* __restrict__ log_b) {
  int b = threadIdx.x;
  if (b >= 32) return;
  float off = ldx(wsb, 0, *dtf);
  float l[8], M = -1e30f;
  #pragma unroll
  for (int s = 0; s < 8; ++s) { l[s] = logits_b[b * 8 + s] + off; M = fmaxf(M, l[s]); }
  float S = 0.0f;
  #pragma unroll
  for (int s = 0; s < 8; ++s) S += __expf(l[s] - M);
  float lgS = slog(S);
  #pragma unroll
  for (int s = 0; s < 8; ++s) log_b[b * 8 + s] = l[s] - M - lgS + LN8;
}

// ---- cross-block group reduction, sentinel-flag protocol (8 blocks/batch) ----
// Round-2 verified config: NSPLIT=8, 512 threads, linear grid.  Slots pre-armed
// to SENT by hipMemsetAsync; all stored partials are clamped-finite so the
// value itself is the arrival flag.  Every block reads the same 64 finalized
// slots and applies the identical shuffle tree -> bit-identical across blocks.
// rp < 64 fresh slots per launch: no reuse, no ABA.
__device__ __forceinline__ float grp_sync_reduce(
    float acc8[8], float (*red)[8],
    unsigned int* gp, int rp, int blkn, int wv, int lane, int tid) {
  #pragma unroll
  for (int m = 1; m < 64; m <<= 1)
    #pragma unroll
    for (int s = 0; s < 8; ++s) acc8[s] += __shfl_xor(acc8[s], m, 64);
  if (lane == 0)
    #pragma unroll
    for (int s = 0; s < 8; ++s) red[wv][s] = acc8[s];
  __syncthreads();
  float x = 0.0f;
  if (tid < 64) {  // wave 0 only; waves 1-7 park at the caller's __syncthreads
    float v = red[tid >> 3][tid & 7];
    v += __shfl_xor(v, 8, 64);
    v += __shfl_xor(v, 16, 64);
    v += __shfl_xor(v, 32, 64);
    if (tid < 8)
      __hip_atomic_store(gp + rp * 64 + blkn * 8 + tid, __float_as_uint(v),
                         __ATOMIC_RELAXED, __HIP_MEMORY_SCOPE_AGENT);
    unsigned int u;
    for (;;) {
      u = __hip_atomic_load(gp + rp * 64 + tid, __ATOMIC_RELAXED, __HIP_MEMORY_SCOPE_AGENT);
      if (__all(u != SENT)) break;
      __builtin_amdgcn_s_sleep(1);
    }
    x = __uint_as_float(u);
    x += __shfl_xor(x, 8, 64);
    x += __shfl_xor(x, 16, 64);
    x += __shfl_xor(x, 32, 64);
    // lanes 0..7 hold full column sums for cols 0..7
  }
  return x;
}

// Fused: d2c head (cdist -> E) + MESH/sinkhorn + upd tail (attn^T @ v partial).
__global__ __launch_bounds__(512, 2) void mesh_kernel(
    const u16* __restrict__ kbf, const u16* __restrict__ vbf,
    const float* __restrict__ qf32, const float* __restrict__ qsq_g,
    const float* __restrict__ log_a_g, const float* __restrict__ inva_g,
    const float* __restrict__ log_b_g, const int* __restrict__ dtf,
    unsigned int* __restrict__ gpart,
    float* __restrict__ updp, void* __restrict__ dout_or_null) {
  const int blkn = blockIdx.x;            // 0..NSPLIT-1: which 512-row slice
  const int b = blockIdx.y;               // batch
  const int tid = threadIdx.x;
  const int dt = *dtf;
  const int n = blkn * 512 + tid;         // this thread's single row

  __shared__ float evP[6][8];
  __shared__ float lb[8], invb[8];
  __shared__ float dv[8];
  __shared__ float red[8][8];
  __shared__ float q_lds[8][256];         // 8 KB: q (f32) for this batch
  __shared__ float qsq_l[8];
  __shared__ float pv_lds[512][8];        // 16 KB: attn rows for the upd tail

  const float la = log_a_g[(size_t)b * N_ + n];
  const float ia = inva_g[(size_t)b * N_ + n];
  unsigned int* gp = gpart + (size_t)b * 64 * 64;

  // stage q, qsq, log_b
  {
    const float* qb = qf32 + (size_t)b * 8 * 256;
    #pragma unroll
    for (int i = tid; i < 2048; i += 512) q_lds[i >> 8][i & 255] = qb[i];
    if (tid < 8) {
      qsq_l[tid] = qsq_g[b * 8 + tid];
      float x = log_b_g[b * 8 + tid];
      lb[tid] = x; invb[tid] = fminf(__expf(-x), 1e20f);
    }
  }
  __syncthreads();

  // ---- head: E[s] = exp(-cdist(k_n, q_s)), ksq computed inline ----
  float E[8], dK[8], eus[5];
  float eu = 0.0f, dup = 0.0f;
  {
    const u16* kp = kbf + ((size_t)b * N_ + n) * D_;
    float accq[8] = {0, 0, 0, 0, 0, 0, 0, 0};
    float kq = 0.0f;
    for (int kc = 0; kc < 256; kc += 8) {
      u16x8 kv = *(const u16x8*)(kp + kc);
      float kf[8];
      #pragma unroll
      for (int j = 0; j < 8; ++j) { kf[j] = bf2f(kv[j]); kq += kf[j] * kf[j]; }
      #pragma unroll
      for (int s = 0; s < 8; ++s) {
        float4 qa = *(const float4*)&q_lds[s][kc];
        float4 qb2 = *(const float4*)&q_lds[s][kc + 4];
        accq[s] += kf[0] * qa.x + kf[1] * qa.y + kf[2] * qa.z + kf[3] * qa.w
                 + kf[4] * qb2.x + kf[5] * qb2.y + kf[6] * qb2.z + kf[7] * qb2.w;
      }
    }
    #pragma unroll
    for (int s = 0; s < 8; ++s) {
      float d2 = kq + qsq_l[s] - 2.0f * accq[s];
      float Cv = sqrtf(fmaxf(d2, 1e-12f));
      E[s] = __expf(-Cv);
    }
  }

  const int wv = tid >> 6, lane = tid & 63;
  int rp = 0;

  for (int mesh = 0; mesh < 4; ++mesh) {
    if (tid < 8) evP[0][tid] = 1.0f;
    __syncthreads();
    // ---- forward sinkhorn (5 iters) ----
    for (int t = 1; t <= 5; ++t) {
      float evp[8];
      #pragma unroll
      for (int s = 0; s < 8; ++s) evp[s] = evP[t - 1][s];
      float su = 0.0f;
      #pragma unroll
      for (int s = 0; s < 8; ++s) su += fminf(E[s] * evp[s], 1e30f);
      float u = la - slog(su);
      eu = fminf(__expf(u), 1e20f);
      eus[t - 1] = eu;
      float acc8[8];
      #pragma unroll
      for (int s = 0; s < 8; ++s) acc8[s] = fminf(E[s] * eu, 1e30f);
      float S = grp_sync_reduce(acc8, red, gp, rp, blkn, wv, lane, tid);
      if (tid < 8) {
        float v = lb[tid] - slog(S);
        evP[t][tid] = fminf(__expf(v), 1e20f);
      }
      ++rp;
      __syncthreads();
    }
    // ---- entropy gradient ----
    {
      float ev5[8];
      #pragma unroll
      for (int s = 0; s < 8; ++s) ev5[s] = evP[5][s];
      float acc8[8];
      dup = 0.0f;
      #pragma unroll
      for (int s = 0; s < 8; ++s) {
        float t1 = fminf(E[s] * eu, 1e30f);
        float P = fminf(t1 * ev5[s], 1e30f);
        float Pe = P + 1e-8f;
        float g = -(__logf(Pe) + P / Pe) * P;
        dK[s] = g; dup += g; acc8[s] = g;
      }
      float S = grp_sync_reduce(acc8, red, gp, rp, blkn, wv, lane, tid);
      if (tid < 8) dv[tid] = cl(S);
      ++rp;
      __syncthreads();
    }
    // ---- backward (t = 5..1; cross-block reduce only needed for t > 1) ----
    for (int t = 5; t >= 1; --t) {
      float evt[8], evtm[8], dvl[8], ibl[8];
      #pragma unroll
      for (int s = 0; s < 8; ++s) { evt[s] = evP[t][s]; evtm[s] = evP[t - 1][s]; dvl[s] = dv[s]; ibl[s] = invb[s]; }
      float eut = eus[t - 1];
      float duv = 0.0f;
      float w8[8];
      #pragma unroll
      for (int s = 0; s < 8; ++s) {
        float a1 = fminf(E[s] * eut, 1e30f);
        float b1 = fminf(a1 * evt[s], 1e30f);
        w8[s] = fminf(b1 * ibl[s], 1e30f);
        duv += cl(dvl[s] * w8[s]);
      }
      float du = ((t == 5) ? dup : 0.0f) - duv;
      float duf = cl(cl(du * ia) * eut);
      float acc8[8];
      #pragma unroll
      for (int s = 0; s < 8; ++s) {
        float ee = fminf(E[s] * evtm[s], 1e30f);
        float zc = cl(ee * duf);
        dK[s] -= cl(dvl[s] * w8[s]) + zc;
        acc8[s] = -zc;
      }
      if (t > 1) {
        float S = grp_sync_reduce(acc8, red, gp, rp, blkn, wv, lane, tid);
        if (tid < 8) dv[tid] = cl(S);
        ++rp;
      }
      __syncthreads();  // also protects evP[0] rewrite at next mesh iter
    }
    // ---- cost update ----
    #pragma unroll
    for (int s = 0; s < 8; ++s) {
      float dkc = fminf(fmaxf(dK[s], -4.0f), 4.0f);
      float Enew = E[s] * __expf(-5.0f * dkc);
      E[s] = fminf(fmaxf(Enew, 1e-35f), 1e30f);
    }
  }

  // ---- final sinkhorn (10 iters) ----
  if (tid < 8) evP[0][tid] = 1.0f;
  __syncthreads();
  for (int t = 1; t <= 10; ++t) {
    int pc = (t - 1) & 1, cc = t & 1;
    float evp[8];
    #pragma unroll
    for (int s = 0; s < 8; ++s) evp[s] = evP[pc][s];
    float su = 0.0f;
    #pragma unroll
    for (int s = 0; s < 8; ++s) su += fminf(E[s] * evp[s], 1e30f);
    eu = fminf(__expf(la - slog(su)), 1e20f);
    float acc8[8];
    #pragma unroll
    for (int s = 0; s < 8; ++s) acc8[s] = fminf(E[s] * eu, 1e30f);
    float S = grp_sync_reduce(acc8, red, gp, rp, blkn, wv, lane, tid);
    if (tid < 8) {
      float v = lb[tid] - slog(S);
      evP[cc][tid] = fminf(__expf(v), 1e20f);
    }
    ++rp;
    __syncthreads();
  }
  float evf[8];
  #pragma unroll
  for (int s = 0; s < 8; ++s) evf[s] = evP[0][s];
  float pv[8];
  #pragma unroll
  for (int s = 0; s < 8; ++s) {
    float t1 = fminf(E[s] * eu, 1e30f);
    pv[s] = fminf(t1 * evf[s], 1e30f);
  }
  if (dout_or_null) {
    #pragma unroll
    for (int s = 0; s < 8; ++s)
      stx(dout_or_null, (size_t)OFF_ATTN + ((size_t)b * 8 + s) * N_ + n, dt, pv[s]);
  }

  // ---- tail: this slice's partial of updates = attn^T @ v ----
  #pragma unroll
  for (int s = 0; s < 8; ++s) pv_lds[tid][s] = pv[s];
  __syncthreads();
  {
    int d = tid & 255, half = tid >> 8;   // half in {0,1}: rows 0-255 / 256-511
    const u16* vp = vbf + ((size_t)b * N_ + blkn * 512 + half * 256) * D_ + d;
    float acc[8] = {0, 0, 0, 0, 0, 0, 0, 0};
    for (int i = 0; i < 256; ++i) {
      float vv = bf2f(vp[(size_t)i * D_]);
      float4 a0 = *(const float4*)&pv_lds[half * 256 + i][0];
      float4 a1 = *(const float4*)&pv_lds[half * 256 + i][4];
      acc[0] += a0.x * vv; acc[1] += a0.y * vv; acc[2] += a0.z * vv; acc[3] += a0.w * vv;
      acc[4] += a1.x * vv; acc[5] += a1.y * vv; acc[6] += a1.z * vv; acc[7] += a1.w * vv;
    }
    __syncthreads();  // all reads of pv_lds done before reuse
    if (half == 1) {
      #pragma unroll
      for (int s = 0; s < 8; ++s) pv_lds[d][s] = acc[s];
    }
    __syncthreads();
    if (half == 0) {
      #pragma unroll
      for (int s = 0; s < 8; ++s) acc[s] += pv_lds[d][s];
      #pragma unroll
      for (int s = 0; s < 8; ++s)
        updp[(((size_t)b * 8 + blkn) * 8 + s) * D_ + d] = acc[s];
    }
  }
}

__global__ __launch_bounds__(256) void gru_mlp_kernel(
    const float* __restrict__ updp, const float* __restrict__ slots_cur,
    const u16* __restrict__ WihT, const u16* __restrict__ WhhT,
    const void* __restrict__ bih, const void* __restrict__ bhh,
    const void* __restrict__ lnms, const void* __restrict__ lnmb,
    const void* __restrict__ W1, const void* __restrict__ b1,
    const void* __restrict__ W2, const void* __restrict__ b2,
    const int* __restrict__ dtf,
    float* __restrict__ slots_next, void* __restrict__ dout_or_null) {
  __shared__ float xs[256], hs[256], hns[256], as_[256];
  __shared__ float red4[4];
  const int dt = *dtf;
  int row = blockIdx.x;
  int b = row >> 3, s = row & 7;
  int tid = threadIdx.x;
  float x = 0.0f;
  #pragma unroll
  for (int c = 0; c < 8; ++c) x += updp[(((size_t)b * 8 + c) * 8 + s) * D_ + tid];
  float h = slots_cur[(size_t)row * D_ + tid];
  xs[tid] = x; hs[tid] = h;
  __syncthreads();
  float gr = ldx(bih, tid, dt), gz = ldx(bih, 256 + tid, dt), gn = ldx(bih, 512 + tid, dt);
  float hr = ldx(bhh, tid, dt), hz = ldx(bhh, 256 + tid, dt), hn_ = ldx(bhh, 512 + tid, dt);
  for (int e = 0; e < 256; ++e) {
    float xe = xs[e], he = hs[e];
    const u16* wi = WihT + e * 768;
    const u16* wh = WhhT + e * 768;
    gr += xe * bf2f(wi[tid]); gz += xe * bf2f(wi[256 + tid]); gn += xe * bf2f(wi[512 + tid]);
    hr += he * bf2f(wh[tid]); hz += he * bf2f(wh[256 + tid]); hn_ += he * bf2f(wh[512 + tid]);
  }
  float r = 1.0f / (1.0f + __expf(-(gr + hr)));
  float z = 1.0f / (1.0f + __expf(-(gz + hz)));
  float nn = tanhf(gn + r * hn_);
  float h2 = (1.0f - z) * nn + z * h;
  float sum = breduce256(h2, red4, tid);
  float sq = breduce256(h2 * h2, red4, tid);
  float mean = sum * (1.0f / D_), var = sq * (1.0f / D_) - mean * mean;
  float rstd = rsqrtf(fmaxf(var, 0.0f) + 1e-5f);
  float hn2 = (h2 - mean) * rstd * ldx(lnms, tid, dt) + ldx(lnmb, tid, dt);
  hns[tid] = hn2;
  __syncthreads();
  float a1 = ldx(b1, tid, dt);
  if (dt) {
    const float* W = (const float*)W1;
    for (int e = 0; e < 256; ++e) a1 += hns[e] * W[e * 256 + tid];
  } else {
    const u16* W = (const u16*)W1;
    for (int e = 0; e < 256; ++e) a1 += hns[e] * bf2f(W[e * 256 + tid]);
  }
  a1 = fmaxf(a1, 0.0f);
  as_[tid] = a1;
  __syncthreads();
  float o = h2 + ldx(b2, tid, dt);
  if (dt) {
    const float* W = (const float*)W2;
    for (int e = 0; e < 256; ++e) o += as_[e] * W[e * 256 + tid];
  } else {
    const u16* W = (const u16*)W2;
    for (int e = 0; e < 256; ++e) o += as_[e] * bf2f(W[e * 256 + tid]);
  }
  slots_next[(size_t)row * D_ + tid] = o;
  if (dout_or_null) {
    stx(dout_or_null, (size_t)row * D_ + tid, dt, o);
    stx(dout_or_null, (size_t)OFF_S2 + (size_t)row * D_ + tid, dt, o);
  }
}

// ---------------- host ----------------

extern "C" void kernel_launch(void* const* d_in, const int* in_sizes, int n_in,
                              void* d_out, int out_size, void* d_ws, size_t ws_size,
                              hipStream_t stream) {
  (void)in_sizes; (void)n_in; (void)out_size;
  const void* inp      = d_in[0];
  const void* slots0   = d_in[1];
  const void* ln_in_s  = d_in[2];
  const void* ln_in_b  = d_in[3];
  const void* ln_sl_s  = d_in[4];
  const void* ln_sl_b  = d_in[5];
  const void* ln_mlp_s = d_in[6];
  const void* ln_mlp_b = d_in[7];
  const void* Wq  = d_in[8];
  const void* Wk  = d_in[9];
  const void* Wv  = d_in[10];
  const void* wiW = d_in[11];
  const void* wsW = d_in[13];
  const void* wsb = d_in[14];
  const void* Wih = d_in[15];
  const void* Whh = d_in[16];
  const void* bih = d_in[17];
  const void* bhh = d_in[18];
  const void* W1  = d_in[19];
  const void* b1  = d_in[20];
  const void* W2  = d_in[21];
  const void* b2  = d_in[22];

  char* ws = (char*)d_ws;
  size_t off = 0;
  auto alloc = [&](size_t bytes) -> void* {
    void* p = ws + off;
    off += (bytes + 255) & ~(size_t)255;
    return p;
  };
  const size_t NR = (size_t)B_ * N_;
  int* dtflag     = (int*)alloc(256);
  float2* stats   = (float2*)alloc(NR * sizeof(float2));
  float* logits_a = (float*)alloc(NR * 4);
  float* log_a    = (float*)alloc(NR * 4);
  float* inva     = (float*)alloc(NR * 4);
  u16* kbf        = (u16*)alloc(NR * D_ * 2);
  u16* vbf        = (u16*)alloc(NR * D_ * 2);
  u16* WkT        = (u16*)alloc(E_ * D_ * 2);
  u16* WvT        = (u16*)alloc(E_ * D_ * 2);
  u16* WihT       = (u16*)alloc(768 * 256 * 2);
  u16* WhhT       = (u16*)alloc(768 * 256 * 2);
  float* qf32     = (float*)alloc((size_t)B_ * 8 * 256 * 4);
  float* q_sq     = (float*)alloc(B_ * 8 * 4);
  float* logits_b = (float*)alloc(B_ * 8 * 4);
  float* log_b    = (float*)alloc(B_ * 8 * 4);
  float* updp     = (float*)alloc((size_t)B_ * 8 * 8 * D_ * 4);
  float* slots_a  = (float*)alloc((size_t)B_ * 8 * D_ * 4);
  float* slots_b  = (float*)alloc((size_t)B_ * 8 * D_ * 4);
  // sentinel-armed reduction slots: per step, per batch, 64 points x 64 dwords
  unsigned int* gpart = (unsigned int*)alloc((size_t)3 * B_ * 64 * 64 * 4);
  if (ws_size < off) return;  // sentinel: absmax==0.934 next round => ws shortage

  hipMemsetAsync(gpart, 0xFF, (size_t)3 * B_ * 64 * 64 * 4, stream);  // arm all slots
  detect_dtype_kernel<<<1, 64, 0, stream>>>((const u16*)inp, dtflag);

  transpose_any_kernel<<<(E_ * D_ + 255) / 256, 256, 0, stream>>>(Wk, WkT, E_, D_, dtflag);
  transpose_any_kernel<<<(E_ * D_ + 255) / 256, 256, 0, stream>>>(Wv, WvT, E_, D_, dtflag);
  transpose_any_kernel<<<(768 * 256 + 255) / 256, 256, 0, stream>>>(Wih, WihT, 768, 256, dtflag);
  transpose_any_kernel<<<(768 * 256 + 255) / 256, 256, 0, stream>>>(Whh, WhhT, 768, 256, dtflag);
  cast_slots_kernel<<<(B_ * 8 * D_) / 256, 256, 0, stream>>>(slots0, slots_a, dtflag);
  ln_stats_kernel<<<NR / 4, 256, 0, stream>>>(inp, ln_in_s, ln_in_b, wiW, dtflag, stats, logits_a);
  amarg_kernel<<<B_, 1024, 0, stream>>>(logits_a, log_a, inva);
  gemm_ln_kernel<<<dim3(NR / 128, 2), 256, 0, stream>>>(inp, stats, ln_in_s, ln_in_b, WkT, dtflag, kbf);
  gemm_ln_kernel<<<dim3(NR / 128, 2), 256, 0, stream>>>(inp, stats, ln_in_s, ln_in_b, WvT, dtflag, vbf);

  float* scur = slots_a;
  float* snext = slots_b;
  for (int step = 0; step < 3; ++step) {
    bool last = (step == 2);
    s1_kernel<<<B_ * 8, 256, 0, stream>>>(scur, ln_sl_s, ln_sl_b, Wq, wsW, dtflag, qf32, q_sq, logits_b);
    bmarg_kernel<<<1, 32, 0, stream>>>(logits_b, wsb, dtflag, log_b);
    mesh_kernel<<<dim3(NSPLIT, B_), 512, 0, stream>>>(kbf, vbf, qf32, q_sq, log_a, inva, log_b,
                                                      dtflag, gpart + (size_t)step * B_ * 64 * 64,
                                                      updp, last ? d_out : (void*)nullptr);
    gru_mlp_kernel<<<B_ * 8, 256, 0, stream>>>(updp, scur, WihT, WhhT, bih, bhh,
                                               ln_mlp_s, ln_mlp_b, W1, b1, W2, b2, dtflag, snext,
                                               last ? d_out : (void*)nullptr);
    float* t = scur; scur = snext; snext = t;
  }
}

// Round 5
// 1027.514 us; speedup vs baseline: 1.2078x; 1.0781x over previous
//
#include <hip/hip_runtime.h>
#include <hip/hip_bf16.h>

#define B_ 32
#define N_ 4096
#define E_ 256
#define D_ 256
#define NS_ 8
#define LN8 2.0794415416798357f
#define OFF_ATTN 65536        // element offset of attn^T in d_out
#define OFF_S2   (65536 + 1048576)  // element offset of second slots copy
#define NSPLIT 8              // blocks per batch in mesh_kernel (512 thr, 1 row/thr)
#define SENT 0xFFFFFFFFu      // -NaN bit pattern; clamped-finite partials never produce it

typedef unsigned short u16;
typedef unsigned short u16x8 __attribute__((ext_vector_type(8)));
typedef __bf16 bf16x8 __attribute__((ext_vector_type(8)));
typedef float floatx4 __attribute__((ext_vector_type(4)));

__device__ __forceinline__ float bf2f(u16 h) {
  unsigned int u = ((unsigned int)h) << 16;
  return __uint_as_float(u);
}
__device__ __forceinline__ u16 f2bf(float f) {
  unsigned int u = __float_as_uint(f);
  unsigned int r = (u + 0x7FFFu + ((u >> 16) & 1u)) >> 16;
  return (u16)r;
}
__device__ __forceinline__ float ldx(const void* p, int i, int dt) {
  return dt ? ((const float*)p)[i] : bf2f(((const u16*)p)[i]);
}
__device__ __forceinline__ void stx(void* p, size_t i, int dt, float v) {
  if (dt) ((float*)p)[i] = v; else ((u16*)p)[i] = f2bf(v);
}
__device__ __forceinline__ float slog(float x) { return __logf(fmaxf(x, 1e-35f)); }
__device__ __forceinline__ float cl(float x) { return fminf(fmaxf(x, -1e30f), 1e30f); }

__device__ __forceinline__ float breduce256(float v, float* red4, int tid) {
  #pragma unroll
  for (int m = 1; m < 64; m <<= 1) v += __shfl_xor(v, m, 64);
  __syncthreads();
  if ((tid & 63) == 0) red4[tid >> 6] = v;
  __syncthreads();
  return red4[0] + red4[1] + red4[2] + red4[3];
}

// ---------------- dtype detector ----------------
__global__ void detect_dtype_kernel(const u16* __restrict__ inp, int* __restrict__ flag) {
  int lane = threadIdx.x & 63;
  int good = 0;
  for (int i = lane; i < 256; i += 64) {
    float x = bf2f(inp[i]);
    float ax = fabsf(x);
    if (x == 0.0f || (ax >= 1e-3f && ax <= 64.0f)) good++;
  }
  #pragma unroll
  for (int m = 1; m < 64; m <<= 1) good += __shfl_xor(good, m, 64);
  if (lane == 0) *flag = (good >= 208) ? 0 : 1;  // 0 = bf16, 1 = f32
}

// ---------------- prep kernels ----------------

__global__ void transpose_any_kernel(const void* __restrict__ src, u16* __restrict__ dst,
                                     int R, int C, const int* __restrict__ dtf) {
  const int dt = *dtf;
  int idx = blockIdx.x * 256 + threadIdx.x;
  if (idx >= R * C) return;
  int r = idx / C, c = idx - r * C;
  dst[c * R + r] = f2bf(ldx(src, idx, dt));
}

__global__ void cast_slots_kernel(const void* __restrict__ src, float* __restrict__ dst,
                                  const int* __restrict__ dtf) {
  const int dt = *dtf;
  int i = blockIdx.x * 256 + threadIdx.x;
  dst[i] = ldx(src, i, dt);
}

// LN stats + input-marginal logits + materialized LN(x) in bf16 (xln).
// xln is bit-identical to what the old fused-GEMM staging produced.
__global__ __launch_bounds__(256) void ln_stats_kernel(
    const void* __restrict__ inp, const void* __restrict__ lns, const void* __restrict__ lnb,
    const void* __restrict__ wiW, const int* __restrict__ dtf,
    u16* __restrict__ xln, float* __restrict__ logits) {
  const int dt = *dtf;
  int row = blockIdx.x * 4 + (threadIdx.x >> 6);
  int lane = threadIdx.x & 63;
  float xs[4];
  if (dt) {
    float4 h = *(const float4*)((const float*)inp + (size_t)row * E_ + lane * 4);
    xs[0] = h.x; xs[1] = h.y; xs[2] = h.z; xs[3] = h.w;
  } else {
    ushort4 h = *(const ushort4*)((const u16*)inp + (size_t)row * E_ + lane * 4);
    xs[0] = bf2f(h.x); xs[1] = bf2f(h.y); xs[2] = bf2f(h.z); xs[3] = bf2f(h.w);
  }
  float s = xs[0] + xs[1] + xs[2] + xs[3];
  float q = xs[0]*xs[0] + xs[1]*xs[1] + xs[2]*xs[2] + xs[3]*xs[3];
  #pragma unroll
  for (int m = 1; m < 64; m <<= 1) { s += __shfl_xor(s, m, 64); q += __shfl_xor(q, m, 64); }
  float mean = s * (1.0f / E_);
  float var = q * (1.0f / E_) - mean * mean;
  float rstd = rsqrtf(fmaxf(var, 0.0f) + 1e-5f);
  int e = lane * 4;
  float d = 0.0f;
  float xn[4];
  #pragma unroll
  for (int j = 0; j < 4; ++j) {
    xn[j] = (xs[j] - mean) * rstd * ldx(lns, e + j, dt) + ldx(lnb, e + j, dt);
    d += xn[j] * ldx(wiW, e + j, dt);
  }
  ushort4 o;
  o.x = f2bf(xn[0]); o.y = f2bf(xn[1]); o.z = f2bf(xn[2]); o.w = f2bf(xn[3]);
  *(ushort4*)(xln + (size_t)row * E_ + e) = o;
  #pragma unroll
  for (int m = 1; m < 64; m <<= 1) d += __shfl_xor(d, m, 64);
  if (lane == 0) logits[row] = d;
}

__global__ __launch_bounds__(1024) void amarg_kernel(const float* __restrict__ logits,
    float* __restrict__ log_a, float* __restrict__ inva) {
  __shared__ float red[16];
  __shared__ float bcast;
  int b = blockIdx.x, tid = threadIdx.x;
  logits += (size_t)b * N_;
  float l[4];
  #pragma unroll
  for (int i = 0; i < 4; ++i) l[i] = logits[tid + i * 1024];
  float mx = fmaxf(fmaxf(l[0], l[1]), fmaxf(l[2], l[3]));
  #pragma unroll
  for (int m = 1; m < 64; m <<= 1) mx = fmaxf(mx, __shfl_xor(mx, m, 64));
  __syncthreads();
  if ((tid & 63) == 0) red[tid >> 6] = mx;
  __syncthreads();
  if (tid == 0) { float v = red[0]; for (int i = 1; i < 16; ++i) v = fmaxf(v, red[i]); bcast = v; }
  __syncthreads();
  float M = bcast;
  float se = 0.0f;
  #pragma unroll
  for (int i = 0; i < 4; ++i) se += __expf(l[i] - M);
  #pragma unroll
  for (int m = 1; m < 64; m <<= 1) se += __shfl_xor(se, m, 64);
  __syncthreads();
  if ((tid & 63) == 0) red[tid >> 6] = se;
  __syncthreads();
  if (tid == 0) { float v = 0; for (int i = 0; i < 16; ++i) v += red[i]; bcast = v; }
  __syncthreads();
  float lgS = slog(bcast);
  #pragma unroll
  for (int i = 0; i < 4; ++i) {
    float lav = l[i] - M - lgS + LN8;
    log_a[tid + i * 1024] = lav;
    inva[tid + i * 1024] = fminf(__expf(-lav), 1e20f);
  }
}

// Pure bf16 GEMM: out[m,n] = sum_k A[m,k] * BT[n,k].  Staging = raw 16B copies.
__global__ __launch_bounds__(256, 2) void gemm_bt_kernel(
    const u16* __restrict__ A, const u16* __restrict__ BT, u16* __restrict__ out) {
  __shared__ __align__(16) u16 Als[128 * 32];
  __shared__ __align__(16) u16 Bls[128 * 32];
  int tid = threadIdx.x;
  int m0 = blockIdx.x * 128, n0 = blockIdx.y * 128;
  int w = tid >> 6, lane = tid & 63;
  int wm = (w & 1) * 64, wn = (w >> 1) * 64;
  int fr = lane & 15, kg = lane >> 4;
  floatx4 acc[4][4];
  #pragma unroll
  for (int i = 0; i < 4; ++i)
    #pragma unroll
    for (int j = 0; j < 4; ++j) acc[i][j] = (floatx4){0.f, 0.f, 0.f, 0.f};
  int sm = tid >> 1;
  int sk0 = (tid & 1) * 16;
  const u16* arow = A + (size_t)(m0 + sm) * E_;
  const u16* brow = BT + (size_t)(n0 + sm) * E_;
  for (int kc = 0; kc < E_; kc += 32) {
    #pragma unroll
    for (int j = 0; j < 16; j += 8) {
      int kk = kc + sk0 + j;
      *(u16x8*)&Als[sm * 32 + sk0 + j] = *(const u16x8*)(arow + kk);
      *(u16x8*)&Bls[sm * 32 + sk0 + j] = *(const u16x8*)(brow + kk);
    }
    __syncthreads();
    bf16x8 af[4], bfv[4];
    #pragma unroll
    for (int im = 0; im < 4; ++im) af[im] = *(const bf16x8*)&Als[(wm + im * 16 + fr) * 32 + kg * 8];
    #pragma unroll
    for (int in = 0; in < 4; ++in) bfv[in] = *(const bf16x8*)&Bls[(wn + in * 16 + fr) * 32 + kg * 8];
    #pragma unroll
    for (int im = 0; im < 4; ++im)
      #pragma unroll
      for (int in = 0; in < 4; ++in)
        acc[im][in] = __builtin_amdgcn_mfma_f32_16x16x32_bf16(af[im], bfv[in], acc[im][in], 0, 0, 0);
    __syncthreads();
  }
  #pragma unroll
  for (int im = 0; im < 4; ++im)
    #pragma unroll
    for (int in = 0; in < 4; ++in)
      #pragma unroll
      for (int r = 0; r < 4; ++r) {
        int row = m0 + wm + im * 16 + kg * 4 + r;
        int col = n0 + wn + in * 16 + fr;
        out[(size_t)row * D_ + col] = f2bf(acc[im][in][r]);
      }
}

// ---------------- per-step kernels ----------------

__global__ __launch_bounds__(256) void s1_kernel(
    const float* __restrict__ slots, const void* __restrict__ lnss, const void* __restrict__ lnsb,
    const void* __restrict__ Wq, const void* __restrict__ wsW, const int* __restrict__ dtf,
    float* __restrict__ qf, float* __restrict__ q_sq, float* __restrict__ logits_b) {
  __shared__ float sn_sh[256];
  __shared__ float red4[4];
  const int dt = *dtf;
  int row = blockIdx.x;
  int tid = threadIdx.x;
  float h = slots[(size_t)row * D_ + tid];
  float sum = breduce256(h, red4, tid);
  float sq = breduce256(h * h, red4, tid);
  float mean = sum * (1.0f / D_), var = sq * (1.0f / D_) - mean * mean;
  float rstd = rsqrtf(fmaxf(var, 0.0f) + 1e-5f);
  float sn = (h - mean) * rstd * ldx(lnss, tid, dt) + ldx(lnsb, tid, dt);
  sn_sh[tid] = sn;
  __syncthreads();
  float acc = 0.0f;
  if (dt) {
    const float* W = (const float*)Wq;
    for (int d = 0; d < 256; ++d) acc += sn_sh[d] * W[d * 256 + tid];
  } else {
    const u16* W = (const u16*)Wq;
    for (int d = 0; d < 256; ++d) acc += sn_sh[d] * bf2f(W[d * 256 + tid]);
  }
  qf[(size_t)row * 256 + tid] = acc;   // f32 q, row = b*8 + s
  float qs = breduce256(acc * acc, red4, tid);
  float lbp = breduce256(sn * ldx(wsW, tid, dt), red4, tid);
  if (tid == 0) { q_sq[row] = qs; logits_b[row] = lbp; }
}

__global__ void bmarg_kernel(const float* __restrict__ logits_b, const void* __restrict__ wsb,
                             const int* __restrict__ dtf, float* __restrict__ log_b) {
  int b = threadIdx.x;
  if (b >= 32) return;
  float off = ldx(wsb, 0, *dtf);
  float l[8], M = -1e30f;
  #pragma unroll
  for (int s = 0; s < 8; ++s) { l[s] = logits_b[b * 8 + s] + off; M = fmaxf(M, l[s]); }
  float S = 0.0f;
  #pragma unroll
  for (int s = 0; s < 8; ++s) S += __expf(l[s] - M);
  float lgS = slog(S);
  #pragma unroll
  for (int s = 0; s < 8; ++s) log_b[b * 8 + s] = l[s] - M - lgS + LN8;
}

// ---- cross-block group reduction, sentinel-flag protocol (8 blocks/batch) ----
// Round-2 verified config: NSPLIT=8, 512 threads, linear grid.  Slots pre-armed
// to SENT by hipMemsetAsync; all stored partials are clamped-finite so the
// value itself is the arrival flag.  Every block reads the same 64 finalized
// slots and applies the identical shuffle tree -> bit-identical across blocks.
// rp < 64 fresh slots per launch: no reuse, no ABA.
__device__ __forceinline__ float grp_sync_reduce(
    float acc8[8], float (*red)[8],
    unsigned int* gp, int rp, int blkn, int wv, int lane, int tid) {
  #pragma unroll
  for (int m = 1; m < 64; m <<= 1)
    #pragma unroll
    for (int s = 0; s < 8; ++s) acc8[s] += __shfl_xor(acc8[s], m, 64);
  if (lane == 0)
    #pragma unroll
    for (int s = 0; s < 8; ++s) red[wv][s] = acc8[s];
  __syncthreads();
  float x = 0.0f;
  if (tid < 64) {  // wave 0 only; waves 1-7 park at the caller's __syncthreads
    float v = red[tid >> 3][tid & 7];
    v += __shfl_xor(v, 8, 64);
    v += __shfl_xor(v, 16, 64);
    v += __shfl_xor(v, 32, 64);
    if (tid < 8)
      __hip_atomic_store(gp + rp * 64 + blkn * 8 + tid, __float_as_uint(v),
                         __ATOMIC_RELAXED, __HIP_MEMORY_SCOPE_AGENT);
    unsigned int u;
    for (;;) {
      u = __hip_atomic_load(gp + rp * 64 + tid, __ATOMIC_RELAXED, __HIP_MEMORY_SCOPE_AGENT);
      if (__all(u != SENT)) break;
      __builtin_amdgcn_s_sleep(1);
    }
    x = __uint_as_float(u);
    x += __shfl_xor(x, 8, 64);
    x += __shfl_xor(x, 16, 64);
    x += __shfl_xor(x, 32, 64);
    // lanes 0..7 hold full column sums for cols 0..7
  }
  return x;
}

// Fused: d2c head (cdist -> E) + MESH/sinkhorn + upd tail (attn^T @ v partial).
__global__ __launch_bounds__(512, 2) void mesh_kernel(
    const u16* __restrict__ kbf, const u16* __restrict__ vbf,
    const float* __restrict__ qf32, const float* __restrict__ qsq_g,
    const float* __restrict__ log_a_g, const float* __restrict__ inva_g,
    const float* __restrict__ log_b_g, const int* __restrict__ dtf,
    unsigned int* __restrict__ gpart,
    float* __restrict__ updp, void* __restrict__ dout_or_null) {
  const int blkn = blockIdx.x;            // 0..NSPLIT-1: which 512-row slice
  const int b = blockIdx.y;               // batch
  const int tid = threadIdx.x;
  const int dt = *dtf;
  const int n = blkn * 512 + tid;         // this thread's single row

  __shared__ float evP[6][8];
  __shared__ float lb[8], invb[8];
  __shared__ float dv[8];
  __shared__ float red[8][8];
  __shared__ float q_lds[8][256];         // 8 KB: q (f32) for this batch
  __shared__ float qsq_l[8];
  __shared__ float pv_lds[512][8];        // 16 KB: attn rows for the upd tail

  const float la = log_a_g[(size_t)b * N_ + n];
  const float ia = inva_g[(size_t)b * N_ + n];
  unsigned int* gp = gpart + (size_t)b * 64 * 64;

  // stage q, qsq, log_b
  {
    const float* qb = qf32 + (size_t)b * 8 * 256;
    #pragma unroll
    for (int i = tid; i < 2048; i += 512) q_lds[i >> 8][i & 255] = qb[i];
    if (tid < 8) {
      qsq_l[tid] = qsq_g[b * 8 + tid];
      float x = log_b_g[b * 8 + tid];
      lb[tid] = x; invb[tid] = fminf(__expf(-x), 1e20f);
    }
  }
  __syncthreads();

  // ---- head: E[s] = exp(-cdist(k_n, q_s)), ksq computed inline ----
  float E[8], dK[8], eus[5];
  float eu = 0.0f, dup = 0.0f;
  {
    const u16* kp = kbf + ((size_t)b * N_ + n) * D_;
    float accq[8] = {0, 0, 0, 0, 0, 0, 0, 0};
    float kq = 0.0f;
    for (int kc = 0; kc < 256; kc += 8) {
      u16x8 kv = *(const u16x8*)(kp + kc);
      float kf[8];
      #pragma unroll
      for (int j = 0; j < 8; ++j) { kf[j] = bf2f(kv[j]); kq += kf[j] * kf[j]; }
      #pragma unroll
      for (int s = 0; s < 8; ++s) {
        float4 qa = *(const float4*)&q_lds[s][kc];
        float4 qb2 = *(const float4*)&q_lds[s][kc + 4];
        accq[s] += kf[0] * qa.x + kf[1] * qa.y + kf[2] * qa.z + kf[3] * qa.w
                 + kf[4] * qb2.x + kf[5] * qb2.y + kf[6] * qb2.z + kf[7] * qb2.w;
      }
    }
    #pragma unroll
    for (int s = 0; s < 8; ++s) {
      float d2 = kq + qsq_l[s] - 2.0f * accq[s];
      float Cv = sqrtf(fmaxf(d2, 1e-12f));
      E[s] = __expf(-Cv);
    }
  }

  const int wv = tid >> 6, lane = tid & 63;
  int rp = 0;

  for (int mesh = 0; mesh < 4; ++mesh) {
    if (tid < 8) evP[0][tid] = 1.0f;
    __syncthreads();
    // ---- forward sinkhorn (5 iters) ----
    for (int t = 1; t <= 5; ++t) {
      float evp[8];
      #pragma unroll
      for (int s = 0; s < 8; ++s) evp[s] = evP[t - 1][s];
      float su = 0.0f;
      #pragma unroll
      for (int s = 0; s < 8; ++s) su += fminf(E[s] * evp[s], 1e30f);
      float u = la - slog(su);
      eu = fminf(__expf(u), 1e20f);
      eus[t - 1] = eu;
      float acc8[8];
      #pragma unroll
      for (int s = 0; s < 8; ++s) acc8[s] = fminf(E[s] * eu, 1e30f);
      float S = grp_sync_reduce(acc8, red, gp, rp, blkn, wv, lane, tid);
      if (tid < 8) {
        float v = lb[tid] - slog(S);
        evP[t][tid] = fminf(__expf(v), 1e20f);
      }
      ++rp;
      __syncthreads();
    }
    // ---- entropy gradient ----
    {
      float ev5[8];
      #pragma unroll
      for (int s = 0; s < 8; ++s) ev5[s] = evP[5][s];
      float acc8[8];
      dup = 0.0f;
      #pragma unroll
      for (int s = 0; s < 8; ++s) {
        float t1 = fminf(E[s] * eu, 1e30f);
        float P = fminf(t1 * ev5[s], 1e30f);
        float Pe = P + 1e-8f;
        float g = -(__logf(Pe) + P / Pe) * P;
        dK[s] = g; dup += g; acc8[s] = g;
      }
      float S = grp_sync_reduce(acc8, red, gp, rp, blkn, wv, lane, tid);
      if (tid < 8) dv[tid] = cl(S);
      ++rp;
      __syncthreads();
    }
    // ---- backward (t = 5..1; cross-block reduce only needed for t > 1) ----
    for (int t = 5; t >= 1; --t) {
      float evt[8], evtm[8], dvl[8], ibl[8];
      #pragma unroll
      for (int s = 0; s < 8; ++s) { evt[s] = evP[t][s]; evtm[s] = evP[t - 1][s]; dvl[s] = dv[s]; ibl[s] = invb[s]; }
      float eut = eus[t - 1];
      float duv = 0.0f;
      float w8[8];
      #pragma unroll
      for (int s = 0; s < 8; ++s) {
        float a1 = fminf(E[s] * eut, 1e30f);
        float b1 = fminf(a1 * evt[s], 1e30f);
        w8[s] = fminf(b1 * ibl[s], 1e30f);
        duv += cl(dvl[s] * w8[s]);
      }
      float du = ((t == 5) ? dup : 0.0f) - duv;
      float duf = cl(cl(du * ia) * eut);
      float acc8[8];
      #pragma unroll
      for (int s = 0; s < 8; ++s) {
        float ee = fminf(E[s] * evtm[s], 1e30f);
        float zc = cl(ee * duf);
        dK[s] -= cl(dvl[s] * w8[s]) + zc;
        acc8[s] = -zc;
      }
      if (t > 1) {
        float S = grp_sync_reduce(acc8, red, gp, rp, blkn, wv, lane, tid);
        if (tid < 8) dv[tid] = cl(S);
        ++rp;
      }
      __syncthreads();  // also protects evP[0] rewrite at next mesh iter
    }
    // ---- cost update ----
    #pragma unroll
    for (int s = 0; s < 8; ++s) {
      float dkc = fminf(fmaxf(dK[s], -4.0f), 4.0f);
      float Enew = E[s] * __expf(-5.0f * dkc);
      E[s] = fminf(fmaxf(Enew, 1e-35f), 1e30f);
    }
  }

  // ---- final sinkhorn (10 iters) ----
  if (tid < 8) evP[0][tid] = 1.0f;
  __syncthreads();
  for (int t = 1; t <= 10; ++t) {
    int pc = (t - 1) & 1, cc = t & 1;
    float evp[8];
    #pragma unroll
    for (int s = 0; s < 8; ++s) evp[s] = evP[pc][s];
    float su = 0.0f;
    #pragma unroll
    for (int s = 0; s < 8; ++s) su += fminf(E[s] * evp[s], 1e30f);
    eu = fminf(__expf(la - slog(su)), 1e20f);
    float acc8[8];
    #pragma unroll
    for (int s = 0; s < 8; ++s) acc8[s] = fminf(E[s] * eu, 1e30f);
    float S = grp_sync_reduce(acc8, red, gp, rp, blkn, wv, lane, tid);
    if (tid < 8) {
      float v = lb[tid] - slog(S);
      evP[cc][tid] = fminf(__expf(v), 1e20f);
    }
    ++rp;
    __syncthreads();
  }
  float evf[8];
  #pragma unroll
  for (int s = 0; s < 8; ++s) evf[s] = evP[0][s];
  float pv[8];
  #pragma unroll
  for (int s = 0; s < 8; ++s) {
    float t1 = fminf(E[s] * eu, 1e30f);
    pv[s] = fminf(t1 * evf[s], 1e30f);
  }
  if (dout_or_null) {
    #pragma unroll
    for (int s = 0; s < 8; ++s)
      stx(dout_or_null, (size_t)OFF_ATTN + ((size_t)b * 8 + s) * N_ + n, dt, pv[s]);
  }

  // ---- tail: this slice's partial of updates = attn^T @ v ----
  #pragma unroll
  for (int s = 0; s < 8; ++s) pv_lds[tid][s] = pv[s];
  __syncthreads();
  {
    int d = tid & 255, half = tid >> 8;   // half in {0,1}: rows 0-255 / 256-511
    const u16* vp = vbf + ((size_t)b * N_ + blkn * 512 + half * 256) * D_ + d;
    float acc[8] = {0, 0, 0, 0, 0, 0, 0, 0};
    for (int i = 0; i < 256; ++i) {
      float vv = bf2f(vp[(size_t)i * D_]);
      float4 a0 = *(const float4*)&pv_lds[half * 256 + i][0];
      float4 a1 = *(const float4*)&pv_lds[half * 256 + i][4];
      acc[0] += a0.x * vv; acc[1] += a0.y * vv; acc[2] += a0.z * vv; acc[3] += a0.w * vv;
      acc[4] += a1.x * vv; acc[5] += a1.y * vv; acc[6] += a1.z * vv; acc[7] += a1.w * vv;
    }
    __syncthreads();  // all reads of pv_lds done before reuse
    if (half == 1) {
      #pragma unroll
      for (int s = 0; s < 8; ++s) pv_lds[d][s] = acc[s];
    }
    __syncthreads();
    if (half == 0) {
      #pragma unroll
      for (int s = 0; s < 8; ++s) acc[s] += pv_lds[d][s];
      #pragma unroll
      for (int s = 0; s < 8; ++s)
        updp[(((size_t)b * 8 + blkn) * 8 + s) * D_ + d] = acc[s];
    }
  }
}

__global__ __launch_bounds__(256) void gru_mlp_kernel(
    const float* __restrict__ updp, const float* __restrict__ slots_cur,
    const u16* __restrict__ WihT, const u16* __restrict__ WhhT,
    const void* __restrict__ bih, const void* __restrict__ bhh,
    const void* __restrict__ lnms, const void* __restrict__ lnmb,
    const void* __restrict__ W1, const void* __restrict__ b1,
    const void* __restrict__ W2, const void* __restrict__ b2,
    const int* __restrict__ dtf,
    float* __restrict__ slots_next, void* __restrict__ dout_or_null) {
  __shared__ float xs[256], hs[256], hns[256], as_[256];
  __shared__ float red4[4];
  const int dt = *dtf;
  int row = blockIdx.x;
  int b = row >> 3, s = row & 7;
  int tid = threadIdx.x;
  float x = 0.0f;
  #pragma unroll
  for (int c = 0; c < 8; ++c) x += updp[(((size_t)b * 8 + c) * 8 + s) * D_ + tid];
  float h = slots_cur[(size_t)row * D_ + tid];
  xs[tid] = x; hs[tid] = h;
  __syncthreads();
  float gr = ldx(bih, tid, dt), gz = ldx(bih, 256 + tid, dt), gn = ldx(bih, 512 + tid, dt);
  float hr = ldx(bhh, tid, dt), hz = ldx(bhh, 256 + tid, dt), hn_ = ldx(bhh, 512 + tid, dt);
  for (int e = 0; e < 256; ++e) {
    float xe = xs[e], he = hs[e];
    const u16* wi = WihT + e * 768;
    const u16* wh = WhhT + e * 768;
    gr += xe * bf2f(wi[tid]); gz += xe * bf2f(wi[256 + tid]); gn += xe * bf2f(wi[512 + tid]);
    hr += he * bf2f(wh[tid]); hz += he * bf2f(wh[256 + tid]); hn_ += he * bf2f(wh[512 + tid]);
  }
  float r = 1.0f / (1.0f + __expf(-(gr + hr)));
  float z = 1.0f / (1.0f + __expf(-(gz + hz)));
  float nn = tanhf(gn + r * hn_);
  float h2 = (1.0f - z) * nn + z * h;
  float sum = breduce256(h2, red4, tid);
  float sq = breduce256(h2 * h2, red4, tid);
  float mean = sum * (1.0f / D_), var = sq * (1.0f / D_) - mean * mean;
  float rstd = rsqrtf(fmaxf(var, 0.0f) + 1e-5f);
  float hn2 = (h2 - mean) * rstd * ldx(lnms, tid, dt) + ldx(lnmb, tid, dt);
  hns[tid] = hn2;
  __syncthreads();
  float a1 = ldx(b1, tid, dt);
  if (dt) {
    const float* W = (const float*)W1;
    for (int e = 0; e < 256; ++e) a1 += hns[e] * W[e * 256 + tid];
  } else {
    const u16* W = (const u16*)W1;
    for (int e = 0; e < 256; ++e) a1 += hns[e] * bf2f(W[e * 256 + tid]);
  }
  a1 = fmaxf(a1, 0.0f);
  as_[tid] = a1;
  __syncthreads();
  float o = h2 + ldx(b2, tid, dt);
  if (dt) {
    const float* W = (const float*)W2;
    for (int e = 0; e < 256; ++e) o += as_[e] * W[e * 256 + tid];
  } else {
    const u16* W = (const u16*)W2;
    for (int e = 0; e < 256; ++e) o += as_[e] * bf2f(W[e * 256 + tid]);
  }
  slots_next[(size_t)row * D_ + tid] = o;
  if (dout_or_null) {
    stx(dout_or_null, (size_t)row * D_ + tid, dt, o);
    stx(dout_or_null, (size_t)OFF_S2 + (size_t)row * D_ + tid, dt, o);
  }
}

// ---------------- host ----------------

extern "C" void kernel_launch(void* const* d_in, const int* in_sizes, int n_in,
                              void* d_out, int out_size, void* d_ws, size_t ws_size,
                              hipStream_t stream) {
  (void)in_sizes; (void)n_in; (void)out_size;
  const void* inp      = d_in[0];
  const void* slots0   = d_in[1];
  const void* ln_in_s  = d_in[2];
  const void* ln_in_b  = d_in[3];
  const void* ln_sl_s  = d_in[4];
  const void* ln_sl_b  = d_in[5];
  const void* ln_mlp_s = d_in[6];
  const void* ln_mlp_b = d_in[7];
  const void* Wq  = d_in[8];
  const void* Wk  = d_in[9];
  const void* Wv  = d_in[10];
  const void* wiW = d_in[11];
  const void* wsW = d_in[13];
  const void* wsb = d_in[14];
  const void* Wih = d_in[15];
  const void* Whh = d_in[16];
  const void* bih = d_in[17];
  const void* bhh = d_in[18];
  const void* W1  = d_in[19];
  const void* b1  = d_in[20];
  const void* W2  = d_in[21];
  const void* b2  = d_in[22];

  char* ws = (char*)d_ws;
  size_t off = 0;
  auto alloc = [&](size_t bytes) -> void* {
    void* p = ws + off;
    off += (bytes + 255) & ~(size_t)255;
    return p;
  };
  const size_t NR = (size_t)B_ * N_;
  int* dtflag     = (int*)alloc(256);
  float* logits_a = (float*)alloc(NR * 4);
  float* log_a    = (float*)alloc(NR * 4);
  float* inva     = (float*)alloc(NR * 4);
  u16* xln        = (u16*)alloc(NR * E_ * 2);
  u16* kbf        = (u16*)alloc(NR * D_ * 2);
  u16* vbf        = (u16*)alloc(NR * D_ * 2);
  u16* WkT        = (u16*)alloc(E_ * D_ * 2);
  u16* WvT        = (u16*)alloc(E_ * D_ * 2);
  u16* WihT       = (u16*)alloc(768 * 256 * 2);
  u16* WhhT       = (u16*)alloc(768 * 256 * 2);
  float* qf32     = (float*)alloc((size_t)B_ * 8 * 256 * 4);
  float* q_sq     = (float*)alloc(B_ * 8 * 4);
  float* logits_b = (float*)alloc(B_ * 8 * 4);
  float* log_b    = (float*)alloc(B_ * 8 * 4);
  float* updp     = (float*)alloc((size_t)B_ * 8 * 8 * D_ * 4);
  float* slots_a  = (float*)alloc((size_t)B_ * 8 * D_ * 4);
  float* slots_b  = (float*)alloc((size_t)B_ * 8 * D_ * 4);
  // sentinel-armed reduction slots: per step, per batch, 64 points x 64 dwords
  unsigned int* gpart = (unsigned int*)alloc((size_t)3 * B_ * 64 * 64 * 4);
  if (ws_size < off) return;  // sentinel: absmax==0.934 next round => ws shortage

  hipMemsetAsync(gpart, 0xFF, (size_t)3 * B_ * 64 * 64 * 4, stream);  // arm all slots
  detect_dtype_kernel<<<1, 64, 0, stream>>>((const u16*)inp, dtflag);

  transpose_any_kernel<<<(E_ * D_ + 255) / 256, 256, 0, stream>>>(Wk, WkT, E_, D_, dtflag);
  transpose_any_kernel<<<(E_ * D_ + 255) / 256, 256, 0, stream>>>(Wv, WvT, E_, D_, dtflag);
  transpose_any_kernel<<<(768 * 256 + 255) / 256, 256, 0, stream>>>(Wih, WihT, 768, 256, dtflag);
  transpose_any_kernel<<<(768 * 256 + 255) / 256, 256, 0, stream>>>(Whh, WhhT, 768, 256, dtflag);
  cast_slots_kernel<<<(B_ * 8 * D_) / 256, 256, 0, stream>>>(slots0, slots_a, dtflag);
  ln_stats_kernel<<<NR / 4, 256, 0, stream>>>(inp, ln_in_s, ln_in_b, wiW, dtflag, xln, logits_a);
  amarg_kernel<<<B_, 1024, 0, stream>>>(logits_a, log_a, inva);
  gemm_bt_kernel<<<dim3(NR / 128, 2), 256, 0, stream>>>(xln, WkT, kbf);
  gemm_bt_kernel<<<dim3(NR / 128, 2), 256, 0, stream>>>(xln, WvT, vbf);

  float* scur = slots_a;
  float* snext = slots_b;
  for (int step = 0; step < 3; ++step) {
    bool last = (step == 2);
    s1_kernel<<<B_ * 8, 256, 0, stream>>>(scur, ln_sl_s, ln_sl_b, Wq, wsW, dtflag, qf32, q_sq, logits_b);
    bmarg_kernel<<<1, 32, 0, stream>>>(logits_b, wsb, dtflag, log_b);
    mesh_kernel<<<dim3(NSPLIT, B_), 512, 0, stream>>>(kbf, vbf, qf32, q_sq, log_a, inva, log_b,
                                                      dtflag, gpart + (size_t)step * B_ * 64 * 64,
                                                      updp, last ? d_out : (void*)nullptr);
    gru_mlp_kernel<<<B_ * 8, 256, 0, stream>>>(updp, scur, WihT, WhhT, bih, bhh,
                                               ln_mlp_s, ln_mlp_b, W1, b1, W2, b2, dtflag, snext,
                                               last ? d_out : (void*)nullptr);
    float* t = scur; scur = snext; snext = t;
  }
}

// Round 6
// 1000.264 us; speedup vs baseline: 1.2407x; 1.0272x over previous
//
#include <hip/hip_runtime.h>
#include <hip/hip_bf16.h>

#define B_ 32
#define N_ 4096
#define E_ 256
#define D_ 256
#define NS_ 8
#define LN8 2.0794415416798357f
#define OFF_ATTN 65536        // element offset of attn^T in d_out
#define OFF_S2   (65536 + 1048576)  // element offset of second slots copy
#define NSPLIT 8              // blocks per batch in mesh_kernel (512 thr, 1 row/thr)
#define SENT 0xFFFFFFFFu      // -NaN bit pattern; clamped-finite partials never produce it

typedef unsigned short u16;
typedef unsigned short u16x8 __attribute__((ext_vector_type(8)));
typedef __bf16 bf16x8 __attribute__((ext_vector_type(8)));
typedef float floatx4 __attribute__((ext_vector_type(4)));

__device__ __forceinline__ float bf2f(u16 h) {
  unsigned int u = ((unsigned int)h) << 16;
  return __uint_as_float(u);
}
__device__ __forceinline__ u16 f2bf(float f) {
  unsigned int u = __float_as_uint(f);
  unsigned int r = (u + 0x7FFFu + ((u >> 16) & 1u)) >> 16;
  return (u16)r;
}
__device__ __forceinline__ float ldx(const void* p, int i, int dt) {
  return dt ? ((const float*)p)[i] : bf2f(((const u16*)p)[i]);
}
__device__ __forceinline__ void stx(void* p, size_t i, int dt, float v) {
  if (dt) ((float*)p)[i] = v; else ((u16*)p)[i] = f2bf(v);
}
__device__ __forceinline__ float slog(float x) { return __logf(fmaxf(x, 1e-35f)); }
__device__ __forceinline__ float cl(float x) { return fminf(fmaxf(x, -1e30f), 1e30f); }

__device__ __forceinline__ float breduce256(float v, float* red4, int tid) {
  #pragma unroll
  for (int m = 1; m < 64; m <<= 1) v += __shfl_xor(v, m, 64);
  __syncthreads();
  if ((tid & 63) == 0) red4[tid >> 6] = v;
  __syncthreads();
  return red4[0] + red4[1] + red4[2] + red4[3];
}

// ---------------- dtype detector ----------------
__global__ void detect_dtype_kernel(const u16* __restrict__ inp, int* __restrict__ flag) {
  int lane = threadIdx.x & 63;
  int good = 0;
  for (int i = lane; i < 256; i += 64) {
    float x = bf2f(inp[i]);
    float ax = fabsf(x);
    if (x == 0.0f || (ax >= 1e-3f && ax <= 64.0f)) good++;
  }
  #pragma unroll
  for (int m = 1; m < 64; m <<= 1) good += __shfl_xor(good, m, 64);
  if (lane == 0) *flag = (good >= 208) ? 0 : 1;  // 0 = bf16, 1 = f32
}

// ---------------- prep kernels ----------------

// Wk and Wv transposed into one [512][256] buffer (rows 0-255 Wk^T, 256-511 Wv^T)
__global__ void tr_kv_kernel(const void* __restrict__ Wk, const void* __restrict__ Wv,
                             u16* __restrict__ WkvT, const int* __restrict__ dtf) {
  const int dt = *dtf;
  int idx = blockIdx.x * 256 + threadIdx.x;   // 0 .. 131071
  int half = idx >> 16, i = idx & 65535;
  int r = i >> 8, c = i & 255;
  const void* src = half ? Wv : Wk;
  WkvT[((size_t)(half * 256 + c)) * 256 + r] = f2bf(ldx(src, i, dt));
}

// Wih and Whh transposed (768x256 -> [256][768]) in one launch
__global__ void tr_gru_kernel(const void* __restrict__ Wih, const void* __restrict__ Whh,
                              u16* __restrict__ WihT, u16* __restrict__ WhhT,
                              const int* __restrict__ dtf) {
  const int dt = *dtf;
  int idx = blockIdx.x * 256 + threadIdx.x;   // 0 .. 393215
  int half = idx >= 196608;
  int i = idx - (half ? 196608 : 0);
  int r = i >> 8, c = i & 255;                // r in 0..767
  u16* dst = half ? WhhT : WihT;
  dst[(size_t)c * 768 + r] = f2bf(ldx(half ? Whh : Wih, i, dt));
}

__global__ void cast_slots_kernel(const void* __restrict__ src, float* __restrict__ dst,
                                  const int* __restrict__ dtf) {
  const int dt = *dtf;
  int i = blockIdx.x * 256 + threadIdx.x;
  dst[i] = ldx(src, i, dt);
}

// LN stats + input-marginal logits + materialized LN(x) in bf16 (xln).
__global__ __launch_bounds__(256) void ln_stats_kernel(
    const void* __restrict__ inp, const void* __restrict__ lns, const void* __restrict__ lnb,
    const void* __restrict__ wiW, const int* __restrict__ dtf,
    u16* __restrict__ xln, float* __restrict__ logits) {
  const int dt = *dtf;
  int row = blockIdx.x * 4 + (threadIdx.x >> 6);
  int lane = threadIdx.x & 63;
  float xs[4];
  if (dt) {
    float4 h = *(const float4*)((const float*)inp + (size_t)row * E_ + lane * 4);
    xs[0] = h.x; xs[1] = h.y; xs[2] = h.z; xs[3] = h.w;
  } else {
    ushort4 h = *(const ushort4*)((const u16*)inp + (size_t)row * E_ + lane * 4);
    xs[0] = bf2f(h.x); xs[1] = bf2f(h.y); xs[2] = bf2f(h.z); xs[3] = bf2f(h.w);
  }
  float s = xs[0] + xs[1] + xs[2] + xs[3];
  float q = xs[0]*xs[0] + xs[1]*xs[1] + xs[2]*xs[2] + xs[3]*xs[3];
  #pragma unroll
  for (int m = 1; m < 64; m <<= 1) { s += __shfl_xor(s, m, 64); q += __shfl_xor(q, m, 64); }
  float mean = s * (1.0f / E_);
  float var = q * (1.0f / E_) - mean * mean;
  float rstd = rsqrtf(fmaxf(var, 0.0f) + 1e-5f);
  int e = lane * 4;
  float d = 0.0f;
  float xn[4];
  #pragma unroll
  for (int j = 0; j < 4; ++j) {
    xn[j] = (xs[j] - mean) * rstd * ldx(lns, e + j, dt) + ldx(lnb, e + j, dt);
    d += xn[j] * ldx(wiW, e + j, dt);
  }
  ushort4 o;
  o.x = f2bf(xn[0]); o.y = f2bf(xn[1]); o.z = f2bf(xn[2]); o.w = f2bf(xn[3]);
  *(ushort4*)(xln + (size_t)row * E_ + e) = o;
  #pragma unroll
  for (int m = 1; m < 64; m <<= 1) d += __shfl_xor(d, m, 64);
  if (lane == 0) logits[row] = d;
}

__global__ __launch_bounds__(1024) void amarg_kernel(const float* __restrict__ logits,
    float* __restrict__ log_a, float* __restrict__ inva) {
  __shared__ float red[16];
  __shared__ float bcast;
  int b = blockIdx.x, tid = threadIdx.x;
  logits += (size_t)b * N_;
  float l[4];
  #pragma unroll
  for (int i = 0; i < 4; ++i) l[i] = logits[tid + i * 1024];
  float mx = fmaxf(fmaxf(l[0], l[1]), fmaxf(l[2], l[3]));
  #pragma unroll
  for (int m = 1; m < 64; m <<= 1) mx = fmaxf(mx, __shfl_xor(mx, m, 64));
  __syncthreads();
  if ((tid & 63) == 0) red[tid >> 6] = mx;
  __syncthreads();
  if (tid == 0) { float v = red[0]; for (int i = 1; i < 16; ++i) v = fmaxf(v, red[i]); bcast = v; }
  __syncthreads();
  float M = bcast;
  float se = 0.0f;
  #pragma unroll
  for (int i = 0; i < 4; ++i) se += __expf(l[i] - M);
  #pragma unroll
  for (int m = 1; m < 64; m <<= 1) se += __shfl_xor(se, m, 64);
  __syncthreads();
  if ((tid & 63) == 0) red[tid >> 6] = se;
  __syncthreads();
  if (tid == 0) { float v = 0; for (int i = 0; i < 16; ++i) v += red[i]; bcast = v; }
  __syncthreads();
  float lgS = slog(bcast);
  #pragma unroll
  for (int i = 0; i < 4; ++i) {
    float lav = l[i] - M - lgS + LN8;
    log_a[tid + i * 1024] = lav;
    inva[tid + i * 1024] = fminf(__expf(-lav), 1e20f);
  }
}

// Pure bf16 GEMM over concatenated [Wk;Wv]^T: one pass over A produces k AND v.
__global__ __launch_bounds__(256, 2) void gemm_bt_kernel(
    const u16* __restrict__ A, const u16* __restrict__ BT,
    u16* __restrict__ kbf, u16* __restrict__ vbf) {
  __shared__ __align__(16) u16 Als[128 * 32];
  __shared__ __align__(16) u16 Bls[128 * 32];
  int tid = threadIdx.x;
  int m0 = blockIdx.x * 128, n0 = blockIdx.y * 128;
  u16* ob = (n0 < 256) ? kbf : vbf;
  int nb = n0 & 255;
  int w = tid >> 6, lane = tid & 63;
  int wm = (w & 1) * 64, wn = (w >> 1) * 64;
  int fr = lane & 15, kg = lane >> 4;
  floatx4 acc[4][4];
  #pragma unroll
  for (int i = 0; i < 4; ++i)
    #pragma unroll
    for (int j = 0; j < 4; ++j) acc[i][j] = (floatx4){0.f, 0.f, 0.f, 0.f};
  int sm = tid >> 1;
  int sk0 = (tid & 1) * 16;
  const u16* arow = A + (size_t)(m0 + sm) * E_;
  const u16* brow = BT + (size_t)(n0 + sm) * E_;
  for (int kc = 0; kc < E_; kc += 32) {
    #pragma unroll
    for (int j = 0; j < 16; j += 8) {
      int kk = kc + sk0 + j;
      *(u16x8*)&Als[sm * 32 + sk0 + j] = *(const u16x8*)(arow + kk);
      *(u16x8*)&Bls[sm * 32 + sk0 + j] = *(const u16x8*)(brow + kk);
    }
    __syncthreads();
    bf16x8 af[4], bfv[4];
    #pragma unroll
    for (int im = 0; im < 4; ++im) af[im] = *(const bf16x8*)&Als[(wm + im * 16 + fr) * 32 + kg * 8];
    #pragma unroll
    for (int in = 0; in < 4; ++in) bfv[in] = *(const bf16x8*)&Bls[(wn + in * 16 + fr) * 32 + kg * 8];
    #pragma unroll
    for (int im = 0; im < 4; ++im)
      #pragma unroll
      for (int in = 0; in < 4; ++in)
        acc[im][in] = __builtin_amdgcn_mfma_f32_16x16x32_bf16(af[im], bfv[in], acc[im][in], 0, 0, 0);
    __syncthreads();
  }
  #pragma unroll
  for (int im = 0; im < 4; ++im)
    #pragma unroll
    for (int in = 0; in < 4; ++in)
      #pragma unroll
      for (int r = 0; r < 4; ++r) {
        int row = m0 + wm + im * 16 + kg * 4 + r;
        int col = nb + wn + in * 16 + fr;
        ob[(size_t)row * D_ + col] = f2bf(acc[im][in][r]);
      }
}

// ---------------- per-step kernels ----------------

// standalone s1 (step 0 only): LN(slots) -> q, q_sq, slot-marginal logits
__global__ __launch_bounds__(256) void s1_kernel(
    const float* __restrict__ slots, const void* __restrict__ lnss, const void* __restrict__ lnsb,
    const void* __restrict__ Wq, const void* __restrict__ wsW, const int* __restrict__ dtf,
    float* __restrict__ qf, float* __restrict__ q_sq, float* __restrict__ logits_b) {
  __shared__ float sn_sh[256];
  __shared__ float red4[4];
  const int dt = *dtf;
  int row = blockIdx.x;
  int tid = threadIdx.x;
  float h = slots[(size_t)row * D_ + tid];
  float sum = breduce256(h, red4, tid);
  float sq = breduce256(h * h, red4, tid);
  float mean = sum * (1.0f / D_), var = sq * (1.0f / D_) - mean * mean;
  float rstd = rsqrtf(fmaxf(var, 0.0f) + 1e-5f);
  float sn = (h - mean) * rstd * ldx(lnss, tid, dt) + ldx(lnsb, tid, dt);
  sn_sh[tid] = sn;
  __syncthreads();
  float acc = 0.0f;
  if (dt) {
    const float* W = (const float*)Wq;
    for (int d = 0; d < 256; ++d) acc += sn_sh[d] * W[d * 256 + tid];
  } else {
    const u16* W = (const u16*)Wq;
    for (int d = 0; d < 256; ++d) acc += sn_sh[d] * bf2f(W[d * 256 + tid]);
  }
  qf[(size_t)row * 256 + tid] = acc;
  float qs = breduce256(acc * acc, red4, tid);
  float lbp = breduce256(sn * ldx(wsW, tid, dt), red4, tid);
  if (tid == 0) { q_sq[row] = qs; logits_b[row] = lbp; }
}

// ---- cross-block group reduction, sentinel-flag protocol (8 blocks/batch) ----
__device__ __forceinline__ float grp_sync_reduce(
    float acc8[8], float (*red)[8],
    unsigned int* gp, int rp, int blkn, int wv, int lane, int tid) {
  #pragma unroll
  for (int m = 1; m < 64; m <<= 1)
    #pragma unroll
    for (int s = 0; s < 8; ++s) acc8[s] += __shfl_xor(acc8[s], m, 64);
  if (lane == 0)
    #pragma unroll
    for (int s = 0; s < 8; ++s) red[wv][s] = acc8[s];
  __syncthreads();
  float x = 0.0f;
  if (tid < 64) {  // wave 0 only; waves 1-7 park at the caller's __syncthreads
    float v = red[tid >> 3][tid & 7];
    v += __shfl_xor(v, 8, 64);
    v += __shfl_xor(v, 16, 64);
    v += __shfl_xor(v, 32, 64);
    if (tid < 8)
      __hip_atomic_store(gp + rp * 64 + blkn * 8 + tid, __float_as_uint(v),
                         __ATOMIC_RELAXED, __HIP_MEMORY_SCOPE_AGENT);
    unsigned int u;
    for (;;) {
      u = __hip_atomic_load(gp + rp * 64 + tid, __ATOMIC_RELAXED, __HIP_MEMORY_SCOPE_AGENT);
      if (__all(u != SENT)) break;
      __builtin_amdgcn_s_sleep(1);
    }
    x = __uint_as_float(u);
    x += __shfl_xor(x, 8, 64);
    x += __shfl_xor(x, 16, 64);
    x += __shfl_xor(x, 32, 64);
    // lanes 0..7 hold full column sums for cols 0..7
  }
  return x;
}

// Fused: bmarg prelude + d2c head (cdist -> E) + MESH/sinkhorn + upd tail.
__global__ __launch_bounds__(512, 2) void mesh_kernel(
    const u16* __restrict__ kbf, const u16* __restrict__ vbf,
    const float* __restrict__ qf32, const float* __restrict__ qsq_g,
    const float* __restrict__ log_a_g, const float* __restrict__ inva_g,
    const float* __restrict__ logits_b_g, const void* __restrict__ wsb,
    const int* __restrict__ dtf,
    unsigned int* __restrict__ gpart,
    float* __restrict__ updp, void* __restrict__ dout_or_null) {
  const int blkn = blockIdx.x;            // 0..NSPLIT-1: which 512-row slice
  const int b = blockIdx.y;               // batch
  const int tid = threadIdx.x;
  const int dt = *dtf;
  const int n = blkn * 512 + tid;         // this thread's single row

  __shared__ float evP[6][8];
  __shared__ float lb[8], invb[8];
  __shared__ float dv[8];
  __shared__ float red[8][8];
  __shared__ float q_lds[8][256];         // 8 KB: q (f32) for this batch
  __shared__ float qsq_l[8];
  __shared__ float pv_lds[512][8];        // 16 KB: attn rows for the upd tail

  const float la = log_a_g[(size_t)b * N_ + n];
  const float ia = inva_g[(size_t)b * N_ + n];
  unsigned int* gp = gpart + (size_t)b * 64 * 64;

  // stage q, qsq; compute log_b in-block (bmarg fold: identical ops on identical
  // inputs in every block -> bit-identical lb/invb across the sync domain)
  {
    const float* qb = qf32 + (size_t)b * 8 * 256;
    #pragma unroll
    for (int i = tid; i < 2048; i += 512) q_lds[i >> 8][i & 255] = qb[i];
    if (tid < 8) {
      qsq_l[tid] = qsq_g[b * 8 + tid];
      float off = ldx(wsb, 0, dt);
      float l[8], M = -1e30f;
      #pragma unroll
      for (int s = 0; s < 8; ++s) { l[s] = logits_b_g[b * 8 + s] + off; M = fmaxf(M, l[s]); }
      float S = 0.0f;
      #pragma unroll
      for (int s = 0; s < 8; ++s) S += __expf(l[s] - M);
      float lgS = slog(S);
      float x = l[tid] - M - lgS + LN8;
      lb[tid] = x; invb[tid] = fminf(__expf(-x), 1e20f);
    }
  }
  __syncthreads();

  // ---- head: E[s] = exp(-cdist(k_n, q_s)), ksq computed inline ----
  float E[8], dK[8], eus[5];
  float eu = 0.0f, dup = 0.0f;
  {
    const u16* kp = kbf + ((size_t)b * N_ + n) * D_;
    float accq[8] = {0, 0, 0, 0, 0, 0, 0, 0};
    float kq = 0.0f;
    for (int kc = 0; kc < 256; kc += 8) {
      u16x8 kv = *(const u16x8*)(kp + kc);
      float kf[8];
      #pragma unroll
      for (int j = 0; j < 8; ++j) { kf[j] = bf2f(kv[j]); kq += kf[j] * kf[j]; }
      #pragma unroll
      for (int s = 0; s < 8; ++s) {
        float4 qa = *(const float4*)&q_lds[s][kc];
        float4 qb2 = *(const float4*)&q_lds[s][kc + 4];
        accq[s] += kf[0] * qa.x + kf[1] * qa.y + kf[2] * qa.z + kf[3] * qa.w
                 + kf[4] * qb2.x + kf[5] * qb2.y + kf[6] * qb2.z + kf[7] * qb2.w;
      }
    }
    #pragma unroll
    for (int s = 0; s < 8; ++s) {
      float d2 = kq + qsq_l[s] - 2.0f * accq[s];
      float Cv = sqrtf(fmaxf(d2, 1e-12f));
      E[s] = __expf(-Cv);
    }
  }

  const int wv = tid >> 6, lane = tid & 63;
  int rp = 0;

  for (int mesh = 0; mesh < 4; ++mesh) {
    if (tid < 8) evP[0][tid] = 1.0f;
    __syncthreads();
    // ---- forward sinkhorn (5 iters) ----
    for (int t = 1; t <= 5; ++t) {
      float evp[8];
      #pragma unroll
      for (int s = 0; s < 8; ++s) evp[s] = evP[t - 1][s];
      float su = 0.0f;
      #pragma unroll
      for (int s = 0; s < 8; ++s) su += fminf(E[s] * evp[s], 1e30f);
      float u = la - slog(su);
      eu = fminf(__expf(u), 1e20f);
      eus[t - 1] = eu;
      float acc8[8];
      #pragma unroll
      for (int s = 0; s < 8; ++s) acc8[s] = fminf(E[s] * eu, 1e30f);
      float S = grp_sync_reduce(acc8, red, gp, rp, blkn, wv, lane, tid);
      if (tid < 8) {
        float v = lb[tid] - slog(S);
        evP[t][tid] = fminf(__expf(v), 1e20f);
      }
      ++rp;
      __syncthreads();
    }
    // ---- entropy gradient ----
    {
      float ev5[8];
      #pragma unroll
      for (int s = 0; s < 8; ++s) ev5[s] = evP[5][s];
      float acc8[8];
      dup = 0.0f;
      #pragma unroll
      for (int s = 0; s < 8; ++s) {
        float t1 = fminf(E[s] * eu, 1e30f);
        float P = fminf(t1 * ev5[s], 1e30f);
        float Pe = P + 1e-8f;
        float g = -(__logf(Pe) + P / Pe) * P;
        dK[s] = g; dup += g; acc8[s] = g;
      }
      float S = grp_sync_reduce(acc8, red, gp, rp, blkn, wv, lane, tid);
      if (tid < 8) dv[tid] = cl(S);
      ++rp;
      __syncthreads();
    }
    // ---- backward (t = 5..1; cross-block reduce only needed for t > 1) ----
    for (int t = 5; t >= 1; --t) {
      float evt[8], evtm[8], dvl[8], ibl[8];
      #pragma unroll
      for (int s = 0; s < 8; ++s) { evt[s] = evP[t][s]; evtm[s] = evP[t - 1][s]; dvl[s] = dv[s]; ibl[s] = invb[s]; }
      float eut = eus[t - 1];
      float duv = 0.0f;
      float w8[8];
      #pragma unroll
      for (int s = 0; s < 8; ++s) {
        float a1 = fminf(E[s] * eut, 1e30f);
        float b1 = fminf(a1 * evt[s], 1e30f);
        w8[s] = fminf(b1 * ibl[s], 1e30f);
        duv += cl(dvl[s] * w8[s]);
      }
      float du = ((t == 5) ? dup : 0.0f) - duv;
      float duf = cl(cl(du * ia) * eut);
      float acc8[8];
      #pragma unroll
      for (int s = 0; s < 8; ++s) {
        float ee = fminf(E[s] * evtm[s], 1e30f);
        float zc = cl(ee * duf);
        dK[s] -= cl(dvl[s] * w8[s]) + zc;
        acc8[s] = -zc;
      }
      if (t > 1) {
        float S = grp_sync_reduce(acc8, red, gp, rp, blkn, wv, lane, tid);
        if (tid < 8) dv[tid] = cl(S);
        ++rp;
      }
      __syncthreads();  // also protects evP[0] rewrite at next mesh iter
    }
    // ---- cost update ----
    #pragma unroll
    for (int s = 0; s < 8; ++s) {
      float dkc = fminf(fmaxf(dK[s], -4.0f), 4.0f);
      float Enew = E[s] * __expf(-5.0f * dkc);
      E[s] = fminf(fmaxf(Enew, 1e-35f), 1e30f);
    }
  }

  // ---- final sinkhorn (10 iters) ----
  if (tid < 8) evP[0][tid] = 1.0f;
  __syncthreads();
  for (int t = 1; t <= 10; ++t) {
    int pc = (t - 1) & 1, cc = t & 1;
    float evp[8];
    #pragma unroll
    for (int s = 0; s < 8; ++s) evp[s] = evP[pc][s];
    float su = 0.0f;
    #pragma unroll
    for (int s = 0; s < 8; ++s) su += fminf(E[s] * evp[s], 1e30f);
    eu = fminf(__expf(la - slog(su)), 1e20f);
    float acc8[8];
    #pragma unroll
    for (int s = 0; s < 8; ++s) acc8[s] = fminf(E[s] * eu, 1e30f);
    float S = grp_sync_reduce(acc8, red, gp, rp, blkn, wv, lane, tid);
    if (tid < 8) {
      float v = lb[tid] - slog(S);
      evP[cc][tid] = fminf(__expf(v), 1e20f);
    }
    ++rp;
    __syncthreads();
  }
  float evf[8];
  #pragma unroll
  for (int s = 0; s < 8; ++s) evf[s] = evP[0][s];
  float pv[8];
  #pragma unroll
  for (int s = 0; s < 8; ++s) {
    float t1 = fminf(E[s] * eu, 1e30f);
    pv[s] = fminf(t1 * evf[s], 1e30f);
  }
  if (dout_or_null) {
    #pragma unroll
    for (int s = 0; s < 8; ++s)
      stx(dout_or_null, (size_t)OFF_ATTN + ((size_t)b * 8 + s) * N_ + n, dt, pv[s]);
  }

  // ---- tail: this slice's partial of updates = attn^T @ v ----
  #pragma unroll
  for (int s = 0; s < 8; ++s) pv_lds[tid][s] = pv[s];
  __syncthreads();
  {
    int d = tid & 255, half = tid >> 8;   // half in {0,1}: rows 0-255 / 256-511
    const u16* vp = vbf + ((size_t)b * N_ + blkn * 512 + half * 256) * D_ + d;
    float acc[8] = {0, 0, 0, 0, 0, 0, 0, 0};
    for (int i = 0; i < 256; ++i) {
      float vv = bf2f(vp[(size_t)i * D_]);
      float4 a0 = *(const float4*)&pv_lds[half * 256 + i][0];
      float4 a1 = *(const float4*)&pv_lds[half * 256 + i][4];
      acc[0] += a0.x * vv; acc[1] += a0.y * vv; acc[2] += a0.z * vv; acc[3] += a0.w * vv;
      acc[4] += a1.x * vv; acc[5] += a1.y * vv; acc[6] += a1.z * vv; acc[7] += a1.w * vv;
    }
    __syncthreads();  // all reads of pv_lds done before reuse
    if (half == 1) {
      #pragma unroll
      for (int s = 0; s < 8; ++s) pv_lds[d][s] = acc[s];
    }
    __syncthreads();
    if (half == 0) {
      #pragma unroll
      for (int s = 0; s < 8; ++s) acc[s] += pv_lds[d][s];
      #pragma unroll
      for (int s = 0; s < 8; ++s)
        updp[(((size_t)b * 8 + blkn) * 8 + s) * D_ + d] = acc[s];
    }
  }
}

// GRU + MLP + (optionally) next step's s1 fused: slots_next row is in registers,
// so LN -> q -> q_sq -> slot-logits append at zero extra memory traffic.
__global__ __launch_bounds__(256) void gru_s1_kernel(
    const float* __restrict__ updp, const float* __restrict__ slots_cur,
    const u16* __restrict__ WihT, const u16* __restrict__ WhhT,
    const void* __restrict__ bih, const void* __restrict__ bhh,
    const void* __restrict__ lnms, const void* __restrict__ lnmb,
    const void* __restrict__ W1, const void* __restrict__ b1,
    const void* __restrict__ W2, const void* __restrict__ b2,
    const void* __restrict__ lnss, const void* __restrict__ lnsb,
    const void* __restrict__ Wq, const void* __restrict__ wsW,
    const int* __restrict__ dtf, int do_s1,
    float* __restrict__ slots_next, float* __restrict__ qf,
    float* __restrict__ q_sq, float* __restrict__ logits_b,
    void* __restrict__ dout_or_null) {
  __shared__ float xs[256], hs[256], hns[256], as_[256];
  __shared__ float red4[4];
  const int dt = *dtf;
  int row = blockIdx.x;
  int b = row >> 3, s = row & 7;
  int tid = threadIdx.x;
  float x = 0.0f;
  #pragma unroll
  for (int c = 0; c < 8; ++c) x += updp[(((size_t)b * 8 + c) * 8 + s) * D_ + tid];
  float h = slots_cur[(size_t)row * D_ + tid];
  xs[tid] = x; hs[tid] = h;
  __syncthreads();
  float gr = ldx(bih, tid, dt), gz = ldx(bih, 256 + tid, dt), gn = ldx(bih, 512 + tid, dt);
  float hr = ldx(bhh, tid, dt), hz = ldx(bhh, 256 + tid, dt), hn_ = ldx(bhh, 512 + tid, dt);
  for (int e = 0; e < 256; ++e) {
    float xe = xs[e], he = hs[e];
    const u16* wi = WihT + e * 768;
    const u16* wh = WhhT + e * 768;
    gr += xe * bf2f(wi[tid]); gz += xe * bf2f(wi[256 + tid]); gn += xe * bf2f(wi[512 + tid]);
    hr += he * bf2f(wh[tid]); hz += he * bf2f(wh[256 + tid]); hn_ += he * bf2f(wh[512 + tid]);
  }
  float r = 1.0f / (1.0f + __expf(-(gr + hr)));
  float z = 1.0f / (1.0f + __expf(-(gz + hz)));
  float nn = tanhf(gn + r * hn_);
  float h2 = (1.0f - z) * nn + z * h;
  float sum = breduce256(h2, red4, tid);
  float sq = breduce256(h2 * h2, red4, tid);
  float mean = sum * (1.0f / D_), var = sq * (1.0f / D_) - mean * mean;
  float rstd = rsqrtf(fmaxf(var, 0.0f) + 1e-5f);
  float hn2 = (h2 - mean) * rstd * ldx(lnms, tid, dt) + ldx(lnmb, tid, dt);
  hns[tid] = hn2;
  __syncthreads();
  float a1 = ldx(b1, tid, dt);
  if (dt) {
    const float* W = (const float*)W1;
    for (int e = 0; e < 256; ++e) a1 += hns[e] * W[e * 256 + tid];
  } else {
    const u16* W = (const u16*)W1;
    for (int e = 0; e < 256; ++e) a1 += hns[e] * bf2f(W[e * 256 + tid]);
  }
  a1 = fmaxf(a1, 0.0f);
  as_[tid] = a1;
  __syncthreads();
  float o = h2 + ldx(b2, tid, dt);
  if (dt) {
    const float* W = (const float*)W2;
    for (int e = 0; e < 256; ++e) o += as_[e] * W[e * 256 + tid];
  } else {
    const u16* W = (const u16*)W2;
    for (int e = 0; e < 256; ++e) o += as_[e] * bf2f(W[e * 256 + tid]);
  }
  slots_next[(size_t)row * D_ + tid] = o;
  if (dout_or_null) {
    stx(dout_or_null, (size_t)row * D_ + tid, dt, o);
    stx(dout_or_null, (size_t)OFF_S2 + (size_t)row * D_ + tid, dt, o);
  }
  if (do_s1) {
    float sum2 = breduce256(o, red4, tid);
    float sq2 = breduce256(o * o, red4, tid);
    float mean2 = sum2 * (1.0f / D_), var2 = sq2 * (1.0f / D_) - mean2 * mean2;
    float rstd2 = rsqrtf(fmaxf(var2, 0.0f) + 1e-5f);
    float sn = (o - mean2) * rstd2 * ldx(lnss, tid, dt) + ldx(lnsb, tid, dt);
    __syncthreads();
    xs[tid] = sn;
    __syncthreads();
    float accq = 0.0f;
    if (dt) {
      const float* W = (const float*)Wq;
      for (int d = 0; d < 256; ++d) accq += xs[d] * W[d * 256 + tid];
    } else {
      const u16* W = (const u16*)Wq;
      for (int d = 0; d < 256; ++d) accq += xs[d] * bf2f(W[d * 256 + tid]);
    }
    qf[(size_t)row * 256 + tid] = accq;
    float qs = breduce256(accq * accq, red4, tid);
    float lbp = breduce256(sn * ldx(wsW, tid, dt), red4, tid);
    if (tid == 0) { q_sq[row] = qs; logits_b[row] = lbp; }
  }
}

// ---------------- host ----------------

extern "C" void kernel_launch(void* const* d_in, const int* in_sizes, int n_in,
                              void* d_out, int out_size, void* d_ws, size_t ws_size,
                              hipStream_t stream) {
  (void)in_sizes; (void)n_in; (void)out_size;
  const void* inp      = d_in[0];
  const void* slots0   = d_in[1];
  const void* ln_in_s  = d_in[2];
  const void* ln_in_b  = d_in[3];
  const void* ln_sl_s  = d_in[4];
  const void* ln_sl_b  = d_in[5];
  const void* ln_mlp_s = d_in[6];
  const void* ln_mlp_b = d_in[7];
  const void* Wq  = d_in[8];
  const void* Wk  = d_in[9];
  const void* Wv  = d_in[10];
  const void* wiW = d_in[11];
  const void* wsW = d_in[13];
  const void* wsb = d_in[14];
  const void* Wih = d_in[15];
  const void* Whh = d_in[16];
  const void* bih = d_in[17];
  const void* bhh = d_in[18];
  const void* W1  = d_in[19];
  const void* b1  = d_in[20];
  const void* W2  = d_in[21];
  const void* b2  = d_in[22];

  char* ws = (char*)d_ws;
  size_t off = 0;
  auto alloc = [&](size_t bytes) -> void* {
    void* p = ws + off;
    off += (bytes + 255) & ~(size_t)255;
    return p;
  };
  const size_t NR = (size_t)B_ * N_;
  int* dtflag     = (int*)alloc(256);
  float* logits_a = (float*)alloc(NR * 4);
  float* log_a    = (float*)alloc(NR * 4);
  float* inva     = (float*)alloc(NR * 4);
  u16* xln        = (u16*)alloc(NR * E_ * 2);
  u16* kbf        = (u16*)alloc(NR * D_ * 2);
  u16* vbf        = (u16*)alloc(NR * D_ * 2);
  u16* WkvT       = (u16*)alloc((size_t)512 * 256 * 2);
  u16* WihT       = (u16*)alloc(768 * 256 * 2);
  u16* WhhT       = (u16*)alloc(768 * 256 * 2);
  float* qf32     = (float*)alloc((size_t)B_ * 8 * 256 * 4);
  float* q_sq     = (float*)alloc(B_ * 8 * 4);
  float* logits_b = (float*)alloc(B_ * 8 * 4);
  float* updp     = (float*)alloc((size_t)B_ * 8 * 8 * D_ * 4);
  float* slots_a  = (float*)alloc((size_t)B_ * 8 * D_ * 4);
  float* slots_b  = (float*)alloc((size_t)B_ * 8 * D_ * 4);
  // sentinel-armed reduction slots: per step, per batch, 64 points x 64 dwords
  unsigned int* gpart = (unsigned int*)alloc((size_t)3 * B_ * 64 * 64 * 4);
  if (ws_size < off) return;  // sentinel: absmax==0.934 next round => ws shortage

  hipMemsetAsync(gpart, 0xFF, (size_t)3 * B_ * 64 * 64 * 4, stream);  // arm all slots
  detect_dtype_kernel<<<1, 64, 0, stream>>>((const u16*)inp, dtflag);

  tr_kv_kernel<<<512, 256, 0, stream>>>(Wk, Wv, WkvT, dtflag);
  tr_gru_kernel<<<1536, 256, 0, stream>>>(Wih, Whh, WihT, WhhT, dtflag);
  cast_slots_kernel<<<(B_ * 8 * D_) / 256, 256, 0, stream>>>(slots0, slots_a, dtflag);
  ln_stats_kernel<<<NR / 4, 256, 0, stream>>>(inp, ln_in_s, ln_in_b, wiW, dtflag, xln, logits_a);
  amarg_kernel<<<B_, 1024, 0, stream>>>(logits_a, log_a, inva);
  gemm_bt_kernel<<<dim3(NR / 128, 4), 256, 0, stream>>>(xln, WkvT, kbf, vbf);

  float* scur = slots_a;
  float* snext = slots_b;
  s1_kernel<<<B_ * 8, 256, 0, stream>>>(scur, ln_sl_s, ln_sl_b, Wq, wsW, dtflag, qf32, q_sq, logits_b);
  for (int step = 0; step < 3; ++step) {
    bool last = (step == 2);
    mesh_kernel<<<dim3(NSPLIT, B_), 512, 0, stream>>>(kbf, vbf, qf32, q_sq, log_a, inva,
                                                      logits_b, wsb, dtflag,
                                                      gpart + (size_t)step * B_ * 64 * 64,
                                                      updp, last ? d_out : (void*)nullptr);
    gru_s1_kernel<<<B_ * 8, 256, 0, stream>>>(updp, scur, WihT, WhhT, bih, bhh,
                                              ln_mlp_s, ln_mlp_b, W1, b1, W2, b2,
                                              ln_sl_s, ln_sl_b, Wq, wsW, dtflag, last ? 0 : 1,
                                              snext, qf32, q_sq, logits_b,
                                              last ? d_out : (void*)nullptr);
    float* t = scur; scur = snext; snext = t;
  }
}

// Round 7
// 993.202 us; speedup vs baseline: 1.2495x; 1.0071x over previous
//
#include <hip/hip_runtime.h>
#include <hip/hip_bf16.h>

#define B_ 32
#define N_ 4096
#define E_ 256
#define D_ 256
#define NS_ 8
#define LN8 2.0794415416798357f
#define OFF_ATTN 65536        // element offset of attn^T in d_out
#define OFF_S2   (65536 + 1048576)  // element offset of second slots copy
#define NSPLIT 8              // blocks per batch in mesh_kernel (512 thr, 1 row/thr)
#define SENT 0xFFFFFFFFu      // -NaN bit pattern; clamped-finite partials never produce it

typedef unsigned short u16;
typedef unsigned short u16x8 __attribute__((ext_vector_type(8)));
typedef __bf16 bf16x8 __attribute__((ext_vector_type(8)));
typedef float floatx4 __attribute__((ext_vector_type(4)));

__device__ __forceinline__ float bf2f(u16 h) {
  unsigned int u = ((unsigned int)h) << 16;
  return __uint_as_float(u);
}
__device__ __forceinline__ u16 f2bf(float f) {
  unsigned int u = __float_as_uint(f);
  unsigned int r = (u + 0x7FFFu + ((u >> 16) & 1u)) >> 16;
  return (u16)r;
}
__device__ __forceinline__ float ldx(const void* p, int i, int dt) {
  return dt ? ((const float*)p)[i] : bf2f(((const u16*)p)[i]);
}
__device__ __forceinline__ void stx(void* p, size_t i, int dt, float v) {
  if (dt) ((float*)p)[i] = v; else ((u16*)p)[i] = f2bf(v);
}
__device__ __forceinline__ float slog(float x) { return __logf(fmaxf(x, 1e-35f)); }
__device__ __forceinline__ float cl(float x) { return fminf(fmaxf(x, -1e30f), 1e30f); }

__device__ __forceinline__ float breduce256(float v, float* red4, int tid) {
  #pragma unroll
  for (int m = 1; m < 64; m <<= 1) v += __shfl_xor(v, m, 64);
  __syncthreads();
  if ((tid & 63) == 0) red4[tid >> 6] = v;
  __syncthreads();
  return red4[0] + red4[1] + red4[2] + red4[3];
}

// 768-thread-block variant: reduction over threads 0-255 only; ALL threads hit
// both barriers (no divergent barrier).  Same tree as breduce256 -> bit-identical.
__device__ __forceinline__ float breduce768(float v, float* red4, int tid) {
  #pragma unroll
  for (int m = 1; m < 64; m <<= 1) v += __shfl_xor(v, m, 64);
  __syncthreads();
  if (tid < 256 && (tid & 63) == 0) red4[tid >> 6] = v;
  __syncthreads();
  return red4[0] + red4[1] + red4[2] + red4[3];
}

// ---------------- dtype detector ----------------
__global__ void detect_dtype_kernel(const u16* __restrict__ inp, int* __restrict__ flag) {
  int lane = threadIdx.x & 63;
  int good = 0;
  for (int i = lane; i < 256; i += 64) {
    float x = bf2f(inp[i]);
    float ax = fabsf(x);
    if (x == 0.0f || (ax >= 1e-3f && ax <= 64.0f)) good++;
  }
  #pragma unroll
  for (int m = 1; m < 64; m <<= 1) good += __shfl_xor(good, m, 64);
  if (lane == 0) *flag = (good >= 208) ? 0 : 1;  // 0 = bf16, 1 = f32
}

// ---------------- prep kernels ----------------

// Wk and Wv transposed into one [512][256] buffer (rows 0-255 Wk^T, 256-511 Wv^T)
__global__ void tr_kv_kernel(const void* __restrict__ Wk, const void* __restrict__ Wv,
                             u16* __restrict__ WkvT, const int* __restrict__ dtf) {
  const int dt = *dtf;
  int idx = blockIdx.x * 256 + threadIdx.x;   // 0 .. 131071
  int half = idx >> 16, i = idx & 65535;
  int r = i >> 8, c = i & 255;
  const void* src = half ? Wv : Wk;
  WkvT[((size_t)(half * 256 + c)) * 256 + r] = f2bf(ldx(src, i, dt));
}

// Wih and Whh cast to bf16, ORIGINAL row-major [768][256] layout (no transpose):
// gru kernel threads stream their own contiguous row with u16x8 loads.
__global__ void cast_w_kernel(const void* __restrict__ Wih, const void* __restrict__ Whh,
                              u16* __restrict__ WihB, u16* __restrict__ WhhB,
                              const int* __restrict__ dtf) {
  const int dt = *dtf;
  int idx = blockIdx.x * 256 + threadIdx.x;   // 0 .. 393215
  int half = idx >= 196608;
  int i = idx - (half ? 196608 : 0);
  u16* dst = half ? WhhB : WihB;
  dst[i] = f2bf(ldx(half ? Whh : Wih, i, dt));
}

__global__ void cast_slots_kernel(const void* __restrict__ src, float* __restrict__ dst,
                                  const int* __restrict__ dtf) {
  const int dt = *dtf;
  int i = blockIdx.x * 256 + threadIdx.x;
  dst[i] = ldx(src, i, dt);
}

// LN stats + input-marginal logits + materialized LN(x) in bf16 (xln).
__global__ __launch_bounds__(256) void ln_stats_kernel(
    const void* __restrict__ inp, const void* __restrict__ lns, const void* __restrict__ lnb,
    const void* __restrict__ wiW, const int* __restrict__ dtf,
    u16* __restrict__ xln, float* __restrict__ logits) {
  const int dt = *dtf;
  int row = blockIdx.x * 4 + (threadIdx.x >> 6);
  int lane = threadIdx.x & 63;
  float xs[4];
  if (dt) {
    float4 h = *(const float4*)((const float*)inp + (size_t)row * E_ + lane * 4);
    xs[0] = h.x; xs[1] = h.y; xs[2] = h.z; xs[3] = h.w;
  } else {
    ushort4 h = *(const ushort4*)((const u16*)inp + (size_t)row * E_ + lane * 4);
    xs[0] = bf2f(h.x); xs[1] = bf2f(h.y); xs[2] = bf2f(h.z); xs[3] = bf2f(h.w);
  }
  float s = xs[0] + xs[1] + xs[2] + xs[3];
  float q = xs[0]*xs[0] + xs[1]*xs[1] + xs[2]*xs[2] + xs[3]*xs[3];
  #pragma unroll
  for (int m = 1; m < 64; m <<= 1) { s += __shfl_xor(s, m, 64); q += __shfl_xor(q, m, 64); }
  float mean = s * (1.0f / E_);
  float var = q * (1.0f / E_) - mean * mean;
  float rstd = rsqrtf(fmaxf(var, 0.0f) + 1e-5f);
  int e = lane * 4;
  float d = 0.0f;
  float xn[4];
  #pragma unroll
  for (int j = 0; j < 4; ++j) {
    xn[j] = (xs[j] - mean) * rstd * ldx(lns, e + j, dt) + ldx(lnb, e + j, dt);
    d += xn[j] * ldx(wiW, e + j, dt);
  }
  ushort4 o;
  o.x = f2bf(xn[0]); o.y = f2bf(xn[1]); o.z = f2bf(xn[2]); o.w = f2bf(xn[3]);
  *(ushort4*)(xln + (size_t)row * E_ + e) = o;
  #pragma unroll
  for (int m = 1; m < 64; m <<= 1) d += __shfl_xor(d, m, 64);
  if (lane == 0) logits[row] = d;
}

__global__ __launch_bounds__(1024) void amarg_kernel(const float* __restrict__ logits,
    float* __restrict__ log_a, float* __restrict__ inva) {
  __shared__ float red[16];
  __shared__ float bcast;
  int b = blockIdx.x, tid = threadIdx.x;
  logits += (size_t)b * N_;
  float l[4];
  #pragma unroll
  for (int i = 0; i < 4; ++i) l[i] = logits[tid + i * 1024];
  float mx = fmaxf(fmaxf(l[0], l[1]), fmaxf(l[2], l[3]));
  #pragma unroll
  for (int m = 1; m < 64; m <<= 1) mx = fmaxf(mx, __shfl_xor(mx, m, 64));
  __syncthreads();
  if ((tid & 63) == 0) red[tid >> 6] = mx;
  __syncthreads();
  if (tid == 0) { float v = red[0]; for (int i = 1; i < 16; ++i) v = fmaxf(v, red[i]); bcast = v; }
  __syncthreads();
  float M = bcast;
  float se = 0.0f;
  #pragma unroll
  for (int i = 0; i < 4; ++i) se += __expf(l[i] - M);
  #pragma unroll
  for (int m = 1; m < 64; m <<= 1) se += __shfl_xor(se, m, 64);
  __syncthreads();
  if ((tid & 63) == 0) red[tid >> 6] = se;
  __syncthreads();
  if (tid == 0) { float v = 0; for (int i = 0; i < 16; ++i) v += red[i]; bcast = v; }
  __syncthreads();
  float lgS = slog(bcast);
  #pragma unroll
  for (int i = 0; i < 4; ++i) {
    float lav = l[i] - M - lgS + LN8;
    log_a[tid + i * 1024] = lav;
    inva[tid + i * 1024] = fminf(__expf(-lav), 1e20f);
  }
}

// Pure bf16 GEMM over concatenated [Wk;Wv]^T: one pass over A produces k AND v.
__global__ __launch_bounds__(256, 2) void gemm_bt_kernel(
    const u16* __restrict__ A, const u16* __restrict__ BT,
    u16* __restrict__ kbf, u16* __restrict__ vbf) {
  __shared__ __align__(16) u16 Als[128 * 32];
  __shared__ __align__(16) u16 Bls[128 * 32];
  int tid = threadIdx.x;
  int m0 = blockIdx.x * 128, n0 = blockIdx.y * 128;
  u16* ob = (n0 < 256) ? kbf : vbf;
  int nb = n0 & 255;
  int w = tid >> 6, lane = tid & 63;
  int wm = (w & 1) * 64, wn = (w >> 1) * 64;
  int fr = lane & 15, kg = lane >> 4;
  floatx4 acc[4][4];
  #pragma unroll
  for (int i = 0; i < 4; ++i)
    #pragma unroll
    for (int j = 0; j < 4; ++j) acc[i][j] = (floatx4){0.f, 0.f, 0.f, 0.f};
  int sm = tid >> 1;
  int sk0 = (tid & 1) * 16;
  const u16* arow = A + (size_t)(m0 + sm) * E_;
  const u16* brow = BT + (size_t)(n0 + sm) * E_;
  for (int kc = 0; kc < E_; kc += 32) {
    #pragma unroll
    for (int j = 0; j < 16; j += 8) {
      int kk = kc + sk0 + j;
      *(u16x8*)&Als[sm * 32 + sk0 + j] = *(const u16x8*)(arow + kk);
      *(u16x8*)&Bls[sm * 32 + sk0 + j] = *(const u16x8*)(brow + kk);
    }
    __syncthreads();
    bf16x8 af[4], bfv[4];
    #pragma unroll
    for (int im = 0; im < 4; ++im) af[im] = *(const bf16x8*)&Als[(wm + im * 16 + fr) * 32 + kg * 8];
    #pragma unroll
    for (int in = 0; in < 4; ++in) bfv[in] = *(const bf16x8*)&Bls[(wn + in * 16 + fr) * 32 + kg * 8];
    #pragma unroll
    for (int im = 0; im < 4; ++im)
      #pragma unroll
      for (int in = 0; in < 4; ++in)
        acc[im][in] = __builtin_amdgcn_mfma_f32_16x16x32_bf16(af[im], bfv[in], acc[im][in], 0, 0, 0);
    __syncthreads();
  }
  #pragma unroll
  for (int im = 0; im < 4; ++im)
    #pragma unroll
    for (int in = 0; in < 4; ++in)
      #pragma unroll
      for (int r = 0; r < 4; ++r) {
        int row = m0 + wm + im * 16 + kg * 4 + r;
        int col = nb + wn + in * 16 + fr;
        ob[(size_t)row * D_ + col] = f2bf(acc[im][in][r]);
      }
}

// ---------------- per-step kernels ----------------

// standalone s1 (step 0 only): LN(slots) -> q, q_sq, slot-marginal logits
__global__ __launch_bounds__(256) void s1_kernel(
    const float* __restrict__ slots, const void* __restrict__ lnss, const void* __restrict__ lnsb,
    const void* __restrict__ Wq, const void* __restrict__ wsW, const int* __restrict__ dtf,
    float* __restrict__ qf, float* __restrict__ q_sq, float* __restrict__ logits_b) {
  __shared__ float sn_sh[256];
  __shared__ float red4[4];
  const int dt = *dtf;
  int row = blockIdx.x;
  int tid = threadIdx.x;
  float h = slots[(size_t)row * D_ + tid];
  float sum = breduce256(h, red4, tid);
  float sq = breduce256(h * h, red4, tid);
  float mean = sum * (1.0f / D_), var = sq * (1.0f / D_) - mean * mean;
  float rstd = rsqrtf(fmaxf(var, 0.0f) + 1e-5f);
  float sn = (h - mean) * rstd * ldx(lnss, tid, dt) + ldx(lnsb, tid, dt);
  sn_sh[tid] = sn;
  __syncthreads();
  float acc = 0.0f;
  if (dt) {
    const float* W = (const float*)Wq;
    for (int d = 0; d < 256; ++d) acc += sn_sh[d] * W[d * 256 + tid];
  } else {
    const u16* W = (const u16*)Wq;
    for (int d = 0; d < 256; ++d) acc += sn_sh[d] * bf2f(W[d * 256 + tid]);
  }
  qf[(size_t)row * 256 + tid] = acc;
  float qs = breduce256(acc * acc, red4, tid);
  float lbp = breduce256(sn * ldx(wsW, tid, dt), red4, tid);
  if (tid == 0) { q_sq[row] = qs; logits_b[row] = lbp; }
}

// ---- cross-block group reduction, sentinel-flag protocol (8 blocks/batch) ----
__device__ __forceinline__ float grp_sync_reduce(
    float acc8[8], float (*red)[8],
    unsigned int* gp, int rp, int blkn, int wv, int lane, int tid) {
  #pragma unroll
  for (int m = 1; m < 64; m <<= 1)
    #pragma unroll
    for (int s = 0; s < 8; ++s) acc8[s] += __shfl_xor(acc8[s], m, 64);
  if (lane == 0)
    #pragma unroll
    for (int s = 0; s < 8; ++s) red[wv][s] = acc8[s];
  __syncthreads();
  float x = 0.0f;
  if (tid < 64) {  // wave 0 only; waves 1-7 park at the caller's __syncthreads
    float v = red[tid >> 3][tid & 7];
    v += __shfl_xor(v, 8, 64);
    v += __shfl_xor(v, 16, 64);
    v += __shfl_xor(v, 32, 64);
    if (tid < 8)
      __hip_atomic_store(gp + rp * 64 + blkn * 8 + tid, __float_as_uint(v),
                         __ATOMIC_RELAXED, __HIP_MEMORY_SCOPE_AGENT);
    unsigned int u;
    for (;;) {
      u = __hip_atomic_load(gp + rp * 64 + tid, __ATOMIC_RELAXED, __HIP_MEMORY_SCOPE_AGENT);
      if (__all(u != SENT)) break;
      __builtin_amdgcn_s_sleep(1);
    }
    x = __uint_as_float(u);
    x += __shfl_xor(x, 8, 64);
    x += __shfl_xor(x, 16, 64);
    x += __shfl_xor(x, 32, 64);
    // lanes 0..7 hold full column sums for cols 0..7
  }
  return x;
}

// Fused: bmarg prelude + d2c head (cdist -> E) + MESH/sinkhorn + upd tail.
__global__ __launch_bounds__(512, 2) void mesh_kernel(
    const u16* __restrict__ kbf, const u16* __restrict__ vbf,
    const float* __restrict__ qf32, const float* __restrict__ qsq_g,
    const float* __restrict__ log_a_g, const float* __restrict__ inva_g,
    const float* __restrict__ logits_b_g, const void* __restrict__ wsb,
    const int* __restrict__ dtf,
    unsigned int* __restrict__ gpart,
    float* __restrict__ updp, void* __restrict__ dout_or_null) {
  const int blkn = blockIdx.x;            // 0..NSPLIT-1: which 512-row slice
  const int b = blockIdx.y;               // batch
  const int tid = threadIdx.x;
  const int dt = *dtf;
  const int n = blkn * 512 + tid;         // this thread's single row

  __shared__ float evP[6][8];
  __shared__ float lb[8], invb[8];
  __shared__ float dv[8];
  __shared__ float red[8][8];
  __shared__ float q_lds[8][256];         // 8 KB: q (f32) for this batch
  __shared__ float qsq_l[8];
  __shared__ float pv_lds[512][8];        // 16 KB: attn rows for the upd tail

  const float la = log_a_g[(size_t)b * N_ + n];
  const float ia = inva_g[(size_t)b * N_ + n];
  unsigned int* gp = gpart + (size_t)b * 64 * 64;

  // stage q, qsq; compute log_b in-block (bmarg fold: identical ops on identical
  // inputs in every block -> bit-identical lb/invb across the sync domain)
  {
    const float* qb = qf32 + (size_t)b * 8 * 256;
    #pragma unroll
    for (int i = tid; i < 2048; i += 512) q_lds[i >> 8][i & 255] = qb[i];
    if (tid < 8) {
      qsq_l[tid] = qsq_g[b * 8 + tid];
      float off = ldx(wsb, 0, dt);
      float l[8], M = -1e30f;
      #pragma unroll
      for (int s = 0; s < 8; ++s) { l[s] = logits_b_g[b * 8 + s] + off; M = fmaxf(M, l[s]); }
      float S = 0.0f;
      #pragma unroll
      for (int s = 0; s < 8; ++s) S += __expf(l[s] - M);
      float lgS = slog(S);
      float x = l[tid] - M - lgS + LN8;
      lb[tid] = x; invb[tid] = fminf(__expf(-x), 1e20f);
    }
  }
  __syncthreads();

  // ---- head: E[s] = exp(-cdist(k_n, q_s)), ksq computed inline ----
  float E[8], dK[8], eus[5];
  float eu = 0.0f, dup = 0.0f;
  {
    const u16* kp = kbf + ((size_t)b * N_ + n) * D_;
    float accq[8] = {0, 0, 0, 0, 0, 0, 0, 0};
    float kq = 0.0f;
    for (int kc = 0; kc < 256; kc += 8) {
      u16x8 kv = *(const u16x8*)(kp + kc);
      float kf[8];
      #pragma unroll
      for (int j = 0; j < 8; ++j) { kf[j] = bf2f(kv[j]); kq += kf[j] * kf[j]; }
      #pragma unroll
      for (int s = 0; s < 8; ++s) {
        float4 qa = *(const float4*)&q_lds[s][kc];
        float4 qb2 = *(const float4*)&q_lds[s][kc + 4];
        accq[s] += kf[0] * qa.x + kf[1] * qa.y + kf[2] * qa.z + kf[3] * qa.w
                 + kf[4] * qb2.x + kf[5] * qb2.y + kf[6] * qb2.z + kf[7] * qb2.w;
      }
    }
    #pragma unroll
    for (int s = 0; s < 8; ++s) {
      float d2 = kq + qsq_l[s] - 2.0f * accq[s];
      float Cv = sqrtf(fmaxf(d2, 1e-12f));
      E[s] = __expf(-Cv);
    }
  }

  const int wv = tid >> 6, lane = tid & 63;
  int rp = 0;

  for (int mesh = 0; mesh < 4; ++mesh) {
    if (tid < 8) evP[0][tid] = 1.0f;
    __syncthreads();
    // ---- forward sinkhorn (5 iters) ----
    for (int t = 1; t <= 5; ++t) {
      float evp[8];
      #pragma unroll
      for (int s = 0; s < 8; ++s) evp[s] = evP[t - 1][s];
      float su = 0.0f;
      #pragma unroll
      for (int s = 0; s < 8; ++s) su += fminf(E[s] * evp[s], 1e30f);
      float u = la - slog(su);
      eu = fminf(__expf(u), 1e20f);
      eus[t - 1] = eu;
      float acc8[8];
      #pragma unroll
      for (int s = 0; s < 8; ++s) acc8[s] = fminf(E[s] * eu, 1e30f);
      float S = grp_sync_reduce(acc8, red, gp, rp, blkn, wv, lane, tid);
      if (tid < 8) {
        float v = lb[tid] - slog(S);
        evP[t][tid] = fminf(__expf(v), 1e20f);
      }
      ++rp;
      __syncthreads();
    }
    // ---- entropy gradient ----
    {
      float ev5[8];
      #pragma unroll
      for (int s = 0; s < 8; ++s) ev5[s] = evP[5][s];
      float acc8[8];
      dup = 0.0f;
      #pragma unroll
      for (int s = 0; s < 8; ++s) {
        float t1 = fminf(E[s] * eu, 1e30f);
        float P = fminf(t1 * ev5[s], 1e30f);
        float Pe = P + 1e-8f;
        float g = -(__logf(Pe) + P / Pe) * P;
        dK[s] = g; dup += g; acc8[s] = g;
      }
      float S = grp_sync_reduce(acc8, red, gp, rp, blkn, wv, lane, tid);
      if (tid < 8) dv[tid] = cl(S);
      ++rp;
      __syncthreads();
    }
    // ---- backward (t = 5..1; cross-block reduce only needed for t > 1) ----
    for (int t = 5; t >= 1; --t) {
      float evt[8], evtm[8], dvl[8], ibl[8];
      #pragma unroll
      for (int s = 0; s < 8; ++s) { evt[s] = evP[t][s]; evtm[s] = evP[t - 1][s]; dvl[s] = dv[s]; ibl[s] = invb[s]; }
      float eut = eus[t - 1];
      float duv = 0.0f;
      float w8[8];
      #pragma unroll
      for (int s = 0; s < 8; ++s) {
        float a1 = fminf(E[s] * eut, 1e30f);
        float b1 = fminf(a1 * evt[s], 1e30f);
        w8[s] = fminf(b1 * ibl[s], 1e30f);
        duv += cl(dvl[s] * w8[s]);
      }
      float du = ((t == 5) ? dup : 0.0f) - duv;
      float duf = cl(cl(du * ia) * eut);
      float acc8[8];
      #pragma unroll
      for (int s = 0; s < 8; ++s) {
        float ee = fminf(E[s] * evtm[s], 1e30f);
        float zc = cl(ee * duf);
        dK[s] -= cl(dvl[s] * w8[s]) + zc;
        acc8[s] = -zc;
      }
      if (t > 1) {
        float S = grp_sync_reduce(acc8, red, gp, rp, blkn, wv, lane, tid);
        if (tid < 8) dv[tid] = cl(S);
        ++rp;
      }
      __syncthreads();  // also protects evP[0] rewrite at next mesh iter
    }
    // ---- cost update ----
    #pragma unroll
    for (int s = 0; s < 8; ++s) {
      float dkc = fminf(fmaxf(dK[s], -4.0f), 4.0f);
      float Enew = E[s] * __expf(-5.0f * dkc);
      E[s] = fminf(fmaxf(Enew, 1e-35f), 1e30f);
    }
  }

  // ---- final sinkhorn (10 iters) ----
  if (tid < 8) evP[0][tid] = 1.0f;
  __syncthreads();
  for (int t = 1; t <= 10; ++t) {
    int pc = (t - 1) & 1, cc = t & 1;
    float evp[8];
    #pragma unroll
    for (int s = 0; s < 8; ++s) evp[s] = evP[pc][s];
    float su = 0.0f;
    #pragma unroll
    for (int s = 0; s < 8; ++s) su += fminf(E[s] * evp[s], 1e30f);
    eu = fminf(__expf(la - slog(su)), 1e20f);
    float acc8[8];
    #pragma unroll
    for (int s = 0; s < 8; ++s) acc8[s] = fminf(E[s] * eu, 1e30f);
    float S = grp_sync_reduce(acc8, red, gp, rp, blkn, wv, lane, tid);
    if (tid < 8) {
      float v = lb[tid] - slog(S);
      evP[cc][tid] = fminf(__expf(v), 1e20f);
    }
    ++rp;
    __syncthreads();
  }
  float evf[8];
  #pragma unroll
  for (int s = 0; s < 8; ++s) evf[s] = evP[0][s];
  float pv[8];
  #pragma unroll
  for (int s = 0; s < 8; ++s) {
    float t1 = fminf(E[s] * eu, 1e30f);
    pv[s] = fminf(t1 * evf[s], 1e30f);
  }
  if (dout_or_null) {
    #pragma unroll
    for (int s = 0; s < 8; ++s)
      stx(dout_or_null, (size_t)OFF_ATTN + ((size_t)b * 8 + s) * N_ + n, dt, pv[s]);
  }

  // ---- tail: this slice's partial of updates = attn^T @ v ----
  #pragma unroll
  for (int s = 0; s < 8; ++s) pv_lds[tid][s] = pv[s];
  __syncthreads();
  {
    int d = tid & 255, half = tid >> 8;   // half in {0,1}: rows 0-255 / 256-511
    const u16* vp = vbf + ((size_t)b * N_ + blkn * 512 + half * 256) * D_ + d;
    float acc[8] = {0, 0, 0, 0, 0, 0, 0, 0};
    for (int i = 0; i < 256; ++i) {
      float vv = bf2f(vp[(size_t)i * D_]);
      float4 a0 = *(const float4*)&pv_lds[half * 256 + i][0];
      float4 a1 = *(const float4*)&pv_lds[half * 256 + i][4];
      acc[0] += a0.x * vv; acc[1] += a0.y * vv; acc[2] += a0.z * vv; acc[3] += a0.w * vv;
      acc[4] += a1.x * vv; acc[5] += a1.y * vv; acc[6] += a1.z * vv; acc[7] += a1.w * vv;
    }
    __syncthreads();  // all reads of pv_lds done before reuse
    if (half == 1) {
      #pragma unroll
      for (int s = 0; s < 8; ++s) pv_lds[d][s] = acc[s];
    }
    __syncthreads();
    if (half == 0) {
      #pragma unroll
      for (int s = 0; s < 8; ++s) acc[s] += pv_lds[d][s];
      #pragma unroll
      for (int s = 0; s < 8; ++s)
        updp[(((size_t)b * 8 + blkn) * 8 + s) * D_ + d] = acc[s];
    }
  }
}

// GRU + MLP + (optionally) next step's s1, 768 threads:
// thread t < 768 computes gate pre-activations gi_t, gh_t by streaming its own
// contiguous bf16 weight row (u16x8 loads); threads 0-255 then combine gates,
// LN, MLP, and the fused s1 tail.  Accumulation order per output is identical
// to the previous version (bias first, e = 0..255 sequential) -> bit-identical.
__global__ __launch_bounds__(768) void gru_s1_kernel(
    const float* __restrict__ updp, const float* __restrict__ slots_cur,
    const u16* __restrict__ WihB, const u16* __restrict__ WhhB,
    const void* __restrict__ bih, const void* __restrict__ bhh,
    const void* __restrict__ lnms, const void* __restrict__ lnmb,
    const void* __restrict__ W1, const void* __restrict__ b1,
    const void* __restrict__ W2, const void* __restrict__ b2,
    const void* __restrict__ lnss, const void* __restrict__ lnsb,
    const void* __restrict__ Wq, const void* __restrict__ wsW,
    const int* __restrict__ dtf, int do_s1,
    float* __restrict__ slots_next, float* __restrict__ qf,
    float* __restrict__ q_sq, float* __restrict__ logits_b,
    void* __restrict__ dout_or_null) {
  __shared__ float xs[256], hs[256], hns[256], as_[256];
  __shared__ float gi_sh[768], gh_sh[768];
  __shared__ float red4[4];
  const int dt = *dtf;
  int row = blockIdx.x;
  int b = row >> 3, s = row & 7;
  int tid = threadIdx.x;
  if (tid < 256) {
    float x = 0.0f;
    #pragma unroll
    for (int c = 0; c < 8; ++c) x += updp[(((size_t)b * 8 + c) * 8 + s) * D_ + tid];
    xs[tid] = x;
    hs[tid] = slots_cur[(size_t)row * D_ + tid];
  }
  __syncthreads();
  // gate pre-activations: one output per thread, vectorized row stream
  {
    float gi = ldx(bih, tid, dt);
    float gh = ldx(bhh, tid, dt);
    const u16* wi = WihB + (size_t)tid * 256;
    const u16* wh = WhhB + (size_t)tid * 256;
    for (int e = 0; e < 256; e += 8) {
      u16x8 a = *(const u16x8*)(wi + e);
      u16x8 c = *(const u16x8*)(wh + e);
      #pragma unroll
      for (int j = 0; j < 8; ++j) gi += xs[e + j] * bf2f(a[j]);
      #pragma unroll
      for (int j = 0; j < 8; ++j) gh += hs[e + j] * bf2f(c[j]);
    }
    gi_sh[tid] = gi; gh_sh[tid] = gh;
  }
  __syncthreads();
  float h2 = 0.0f;
  if (tid < 256) {
    float r = 1.0f / (1.0f + __expf(-(gi_sh[tid] + gh_sh[tid])));
    float z = 1.0f / (1.0f + __expf(-(gi_sh[256 + tid] + gh_sh[256 + tid])));
    float nn = tanhf(gi_sh[512 + tid] + r * gh_sh[512 + tid]);
    h2 = (1.0f - z) * nn + z * hs[tid];
  }
  float sum = breduce768(h2, red4, tid);
  float sq = breduce768(h2 * h2, red4, tid);
  float mean = sum * (1.0f / D_), var = sq * (1.0f / D_) - mean * mean;
  float rstd = rsqrtf(fmaxf(var, 0.0f) + 1e-5f);
  if (tid < 256) {
    float hn2 = (h2 - mean) * rstd * ldx(lnms, tid, dt) + ldx(lnmb, tid, dt);
    hns[tid] = hn2;
  }
  __syncthreads();
  float o = 0.0f;
  if (tid < 256) {
    float a1 = ldx(b1, tid, dt);
    if (dt) {
      const float* W = (const float*)W1;
      for (int e = 0; e < 256; ++e) a1 += hns[e] * W[e * 256 + tid];
    } else {
      const u16* W = (const u16*)W1;
      for (int e = 0; e < 256; ++e) a1 += hns[e] * bf2f(W[e * 256 + tid]);
    }
    as_[tid] = fmaxf(a1, 0.0f);
  }
  __syncthreads();
  if (tid < 256) {
    o = h2 + ldx(b2, tid, dt);
    if (dt) {
      const float* W = (const float*)W2;
      for (int e = 0; e < 256; ++e) o += as_[e] * W[e * 256 + tid];
    } else {
      const u16* W = (const u16*)W2;
      for (int e = 0; e < 256; ++e) o += as_[e] * bf2f(W[e * 256 + tid]);
    }
    slots_next[(size_t)row * D_ + tid] = o;
    if (dout_or_null) {
      stx(dout_or_null, (size_t)row * D_ + tid, dt, o);
      stx(dout_or_null, (size_t)OFF_S2 + (size_t)row * D_ + tid, dt, o);
    }
  }
  if (do_s1) {
    float sum2 = breduce768(o, red4, tid);
    float sq2 = breduce768(o * o, red4, tid);
    float mean2 = sum2 * (1.0f / D_), var2 = sq2 * (1.0f / D_) - mean2 * mean2;
    float rstd2 = rsqrtf(fmaxf(var2, 0.0f) + 1e-5f);
    float sn = 0.0f;
    __syncthreads();
    if (tid < 256) {
      sn = (o - mean2) * rstd2 * ldx(lnss, tid, dt) + ldx(lnsb, tid, dt);
      xs[tid] = sn;
    }
    __syncthreads();
    float accq = 0.0f;
    if (tid < 256) {
      if (dt) {
        const float* W = (const float*)Wq;
        for (int d = 0; d < 256; ++d) accq += xs[d] * W[d * 256 + tid];
      } else {
        const u16* W = (const u16*)Wq;
        for (int d = 0; d < 256; ++d) accq += xs[d] * bf2f(W[d * 256 + tid]);
      }
      qf[(size_t)row * 256 + tid] = accq;
    }
    float qs = breduce768(accq * accq, red4, tid);
    float lbp = breduce768(tid < 256 ? sn * ldx(wsW, tid, dt) : 0.0f, red4, tid);
    if (tid == 0) { q_sq[row] = qs; logits_b[row] = lbp; }
  }
}

// ---------------- host ----------------

extern "C" void kernel_launch(void* const* d_in, const int* in_sizes, int n_in,
                              void* d_out, int out_size, void* d_ws, size_t ws_size,
                              hipStream_t stream) {
  (void)in_sizes; (void)n_in; (void)out_size;
  const void* inp      = d_in[0];
  const void* slots0   = d_in[1];
  const void* ln_in_s  = d_in[2];
  const void* ln_in_b  = d_in[3];
  const void* ln_sl_s  = d_in[4];
  const void* ln_sl_b  = d_in[5];
  const void* ln_mlp_s = d_in[6];
  const void* ln_mlp_b = d_in[7];
  const void* Wq  = d_in[8];
  const void* Wk  = d_in[9];
  const void* Wv  = d_in[10];
  const void* wiW = d_in[11];
  const void* wsW = d_in[13];
  const void* wsb = d_in[14];
  const void* Wih = d_in[15];
  const void* Whh = d_in[16];
  const void* bih = d_in[17];
  const void* bhh = d_in[18];
  const void* W1  = d_in[19];
  const void* b1  = d_in[20];
  const void* W2  = d_in[21];
  const void* b2  = d_in[22];

  char* ws = (char*)d_ws;
  size_t off = 0;
  auto alloc = [&](size_t bytes) -> void* {
    void* p = ws + off;
    off += (bytes + 255) & ~(size_t)255;
    return p;
  };
  const size_t NR = (size_t)B_ * N_;
  int* dtflag     = (int*)alloc(256);
  float* logits_a = (float*)alloc(NR * 4);
  float* log_a    = (float*)alloc(NR * 4);
  float* inva     = (float*)alloc(NR * 4);
  u16* xln        = (u16*)alloc(NR * E_ * 2);
  u16* kbf        = (u16*)alloc(NR * D_ * 2);
  u16* vbf        = (u16*)alloc(NR * D_ * 2);
  u16* WkvT       = (u16*)alloc((size_t)512 * 256 * 2);
  u16* WihB       = (u16*)alloc(768 * 256 * 2);
  u16* WhhB       = (u16*)alloc(768 * 256 * 2);
  float* qf32     = (float*)alloc((size_t)B_ * 8 * 256 * 4);
  float* q_sq     = (float*)alloc(B_ * 8 * 4);
  float* logits_b = (float*)alloc(B_ * 8 * 4);
  float* updp     = (float*)alloc((size_t)B_ * 8 * 8 * D_ * 4);
  float* slots_a  = (float*)alloc((size_t)B_ * 8 * D_ * 4);
  float* slots_b  = (float*)alloc((size_t)B_ * 8 * D_ * 4);
  // sentinel-armed reduction slots: per step, per batch, 64 points x 64 dwords
  unsigned int* gpart = (unsigned int*)alloc((size_t)3 * B_ * 64 * 64 * 4);
  if (ws_size < off) return;  // sentinel: absmax==0.934 next round => ws shortage

  hipMemsetAsync(gpart, 0xFF, (size_t)3 * B_ * 64 * 64 * 4, stream);  // arm all slots
  detect_dtype_kernel<<<1, 64, 0, stream>>>((const u16*)inp, dtflag);

  tr_kv_kernel<<<512, 256, 0, stream>>>(Wk, Wv, WkvT, dtflag);
  cast_w_kernel<<<1536, 256, 0, stream>>>(Wih, Whh, WihB, WhhB, dtflag);
  cast_slots_kernel<<<(B_ * 8 * D_) / 256, 256, 0, stream>>>(slots0, slots_a, dtflag);
  ln_stats_kernel<<<NR / 4, 256, 0, stream>>>(inp, ln_in_s, ln_in_b, wiW, dtflag, xln, logits_a);
  amarg_kernel<<<B_, 1024, 0, stream>>>(logits_a, log_a, inva);
  gemm_bt_kernel<<<dim3(NR / 128, 4), 256, 0, stream>>>(xln, WkvT, kbf, vbf);

  float* scur = slots_a;
  float* snext = slots_b;
  s1_kernel<<<B_ * 8, 256, 0, stream>>>(scur, ln_sl_s, ln_sl_b, Wq, wsW, dtflag, qf32, q_sq, logits_b);
  for (int step = 0; step < 3; ++step) {
    bool last = (step == 2);
    mesh_kernel<<<dim3(NSPLIT, B_), 512, 0, stream>>>(kbf, vbf, qf32, q_sq, log_a, inva,
                                                      logits_b, wsb, dtflag,
                                                      gpart + (size_t)step * B_ * 64 * 64,
                                                      updp, last ? d_out : (void*)nullptr);
    gru_s1_kernel<<<B_ * 8, 768, 0, stream>>>(updp, scur, WihB, WhhB, bih, bhh,
                                              ln_mlp_s, ln_mlp_b, W1, b1, W2, b2,
                                              ln_sl_s, ln_sl_b, Wq, wsW, dtflag, last ? 0 : 1,
                                              snext, qf32, q_sq, logits_b,
                                              last ? d_out : (void*)nullptr);
    float* t = scur; scur = snext; snext = t;
  }
}